// Round 14
// baseline (523.098 us; speedup 1.0000x reference)
//
#include <hip/hip_runtime.h>

#define DIM 4096
#define HD 128
#define NH 32
#define NKV 8
#define SEQ 2048
#define BATCH 2
#define MTOT (BATCH*SEQ)   // 4096 rows total
#define GK DIM             // K dim of every GEMM

typedef __bf16 bf16;
typedef __bf16 bf16x4 __attribute__((ext_vector_type(4)));
typedef __bf16 bf16x8 __attribute__((ext_vector_type(8)));
typedef float f32x4 __attribute__((ext_vector_type(4)));

#define NL2T (-13.287712379549449f / 64.f)   // -log2(10000)/(HD/2)

__device__ __forceinline__ void gload_lds16(const void* g, void* l) {
    __builtin_amdgcn_global_load_lds(
        (const __attribute__((address_space(1))) void*)g,
        (__attribute__((address_space(3))) void*)l, 16, 0, 0);
}

// ---------------- 64x64 transpose-convert tile: fp32 [K][N] -> bf16 [N][K] --
__device__ __forceinline__ void tconv64_tile(const float* __restrict__ in,
                                             bf16* __restrict__ out,
                                             int N, int K, int bx, int by,
                                             float t[64][65], int tid) {
    int rr = tid >> 4;              // 0..15
    int cc = (tid & 15) * 4;        // 0..60
    const float* ip = in + ((size_t)(by * 64 + rr)) * N + bx * 64 + cc;
#pragma unroll
    for (int p = 0; p < 4; ++p) {
        float4 v = *(const float4*)(ip + (size_t)p * 16 * N);
        t[rr + p * 16][cc + 0] = v.x;
        t[rr + p * 16][cc + 1] = v.y;
        t[rr + p * 16][cc + 2] = v.z;
        t[rr + p * 16][cc + 3] = v.w;
    }
    __syncthreads();
#pragma unroll
    for (int p = 0; p < 4; ++p) {
        int n = rr + p * 16;
        bf16x4 o;
#pragma unroll
        for (int j = 0; j < 4; ++j) o[j] = (bf16)t[cc + j][n];
        *(bf16x4*)(out + (size_t)(bx * 64 + n) * K + by * 64 + cc) = o;
    }
}

// ---------------- fused prep: x->bf16 convert + wq/wk/wv transpose-convert --
__global__ __launch_bounds__(256) void prep(const float* __restrict__ x,
                                            const float* __restrict__ wq,
                                            const float* __restrict__ wk,
                                            const float* __restrict__ wv,
                                            bf16* __restrict__ xb,
                                            bf16* __restrict__ wqt,
                                            bf16* __restrict__ wkt,
                                            bf16* __restrict__ wvt) {
    __shared__ float t[64][65];
    const int bid = blockIdx.x, tid = threadIdx.x;
    if (bid < 8192) {                       // x convert: 8192*256*8 = MTOT*DIM
        int i = bid * 256 + tid;
        const float4* p = (const float4*)(x + (size_t)i * 8);
        float4 a = p[0], b = p[1];
        bf16x8 v;
        v[0]=(bf16)a.x; v[1]=(bf16)a.y; v[2]=(bf16)a.z; v[3]=(bf16)a.w;
        v[4]=(bf16)b.x; v[5]=(bf16)b.y; v[6]=(bf16)b.z; v[7]=(bf16)b.w;
        *(bf16x8*)(xb + (size_t)i * 8) = v;
    } else if (bid < 8192 + 4096) {         // wq: 64x64 tiles
        int b2 = bid - 8192;
        tconv64_tile(wq, wqt, DIM, DIM, b2 & 63, b2 >> 6, t, tid);
    } else if (bid < 8192 + 4096 + 1024) {  // wk
        int b2 = bid - (8192 + 4096);
        tconv64_tile(wk, wkt, 1024, DIM, b2 & 15, b2 >> 4, t, tid);
    } else {                                // wv
        int b2 = bid - (8192 + 4096 + 1024);
        tconv64_tile(wv, wvt, 1024, DIM, b2 & 15, b2 >> 4, t, tid);
    }
}

// ---------------- merged wo-transpose + K-proj + V^T-proj (one launch) -----
// blocks 0..4095: wo [K][N] -> wo^T bf16 into wqt (wqt free: Q-proj done).
//   tconv FIRST so these short memory-bound blocks fill CUs and the gemm
//   blocks backfill to run concurrently (gemm-first would serialize the tail).
// blocks 4096..4351: kb = xb * wkt^T (RoPE fused in epilogue).
// blocks 4352..4607: vtb = wvt * xb^T.
// __sinf/__cosf ONLY (sincosf's OCML call spilled acc to scratch: R11).
__global__ __launch_bounds__(256, 2) void gemm_kv(const bf16* __restrict__ xb,
                                                  const bf16* __restrict__ wkt,
                                                  const bf16* __restrict__ wvt,
                                                  bf16* __restrict__ kb,
                                                  bf16* __restrict__ vtb,
                                                  const float* __restrict__ wo,
                                                  bf16* __restrict__ wot) {
    __shared__ alignas(16) bf16 sA[2][128 * 32];
    __shared__ alignas(16) bf16 sB[2][128 * 32];
    __shared__ float t[64][65];
    const int tid = threadIdx.x;
    const int bid = blockIdx.x;

    if (bid < 4096) {                       // wo transpose-convert
        tconv64_tile(wo, wot, DIM, DIM, bid & 63, bid >> 6, t, tid);
        return;
    }

    const int g = bid - 4096;
    const int lane = tid & 63, wid = tid >> 6;
    const int wm = wid >> 1, wn = wid & 1;

    const bf16 *A, *Bt;
    bf16* out0;
    int N, m0, n0;
    const bool isK = (g < 256);
    if (isK) {
        A = xb; Bt = wkt; out0 = kb; N = 1024;
        m0 = (g >> 3) * 128; n0 = (g & 7) * 128;
    } else {
        int b2 = g - 256;
        A = wvt; Bt = xb; out0 = vtb; N = MTOT;
        m0 = (b2 >> 5) * 128; n0 = (b2 & 31) * 128;
    }

    auto stage = [&](int buf, int kt) {
#pragma unroll
        for (int it = 0; it < 2; ++it) {
            int slot = it * 256 + tid;
            int row = slot >> 2, s = slot & 3;
            gload_lds16(A + (size_t)(m0 + row) * GK + kt * 32 + s * 8, &sA[buf][slot * 8]);
            gload_lds16(Bt + (size_t)(n0 + row) * GK + kt * 32 + s * 8, &sB[buf][slot * 8]);
        }
    };

    f32x4 acc[4][4] = {};
    stage(0, 0);
    __syncthreads();
    int cur = 0;
    for (int kt = 0; kt < GK / 32; ++kt) {
        if (kt + 1 < GK / 32) stage(cur ^ 1, kt + 1);
        bf16x8 bF[4], aF[4];
#pragma unroll
        for (int i = 0; i < 4; ++i)
            bF[i] = *(const bf16x8*)&sB[cur][(wn * 64 + i * 16 + (lane & 15)) * 32 + (lane >> 4) * 8];
#pragma unroll
        for (int i = 0; i < 4; ++i)
            aF[i] = *(const bf16x8*)&sA[cur][(wm * 64 + i * 16 + (lane & 15)) * 32 + (lane >> 4) * 8];
#pragma unroll
        for (int mi = 0; mi < 4; ++mi)
#pragma unroll
            for (int ni = 0; ni < 4; ++ni)
                acc[mi][ni] = __builtin_amdgcn_mfma_f32_16x16x32_bf16(aF[mi], bF[ni], acc[mi][ni], 0, 0, 0);
        __syncthreads();
        cur ^= 1;
    }

    const int lrow = lane & 15;
    if (isK) {
        // fused RoPE epilogue: d = col&127, pair in lane^1, pos = row&2047
        float inv4[4];
#pragma unroll
        for (int ni = 0; ni < 4; ++ni) {
            int d = (wn * 64 + ni * 16 + lrow) & 127;
            inv4[ni] = exp2f(NL2T * (float)(d >> 1));
        }
        const bool ev = (lrow & 1) == 0;
#pragma unroll
        for (int mi = 0; mi < 4; ++mi)
#pragma unroll
            for (int ni = 0; ni < 4; ++ni)
#pragma unroll
                for (int r = 0; r < 4; ++r) {
                    int row = m0 + wm * 64 + mi * 16 + (lane >> 4) * 4 + r;
                    int col = n0 + wn * 64 + ni * 16 + lrow;
                    float v = acc[mi][ni][r];
                    float p = __shfl_xor(v, 1, 64);
                    float ang = (float)(row & (SEQ - 1)) * inv4[ni];
                    float sn = __sinf(ang), cs = __cosf(ang);
                    float o = v * cs + (ev ? -p * sn : p * sn);
                    out0[(size_t)row * N + col] = (bf16)o;
                }
    } else {
#pragma unroll
        for (int mi = 0; mi < 4; ++mi)
#pragma unroll
            for (int ni = 0; ni < 4; ++ni)
#pragma unroll
                for (int r = 0; r < 4; ++r) {
                    int row = m0 + wm * 64 + mi * 16 + (lane >> 4) * 4 + r;
                    int col = n0 + wn * 64 + ni * 16 + lrow;
                    out0[(size_t)row * N + col] = (bf16)acc[mi][ni][r];
                }
    }
}

// ---------------- 256x256 deep-pipelined GEMM (R7 schedule, best measured) --
// Phase p (one 32-wide K-half): [12 ds_read B-first][stage next region]
// [vmcnt(4)][s_barrier][lgkmcnt(0)+sched_barrier][setprio + 32 MFMA].
// MODE 0: bf16 out. MODE 1: bf16 out + fused RoPE (oscale folded). MODE 2: f32.
template <int MODE>
__global__ __launch_bounds__(512, 2) void gemm8(const bf16* __restrict__ A,
                                                const bf16* __restrict__ Bt,
                                                void* __restrict__ outp, int N,
                                                float oscale) {
    __shared__ alignas(16) char sA[2][2][16384];
    __shared__ alignas(16) char sB[2][2][16384];
    const int tid = threadIdx.x, lane = tid & 63;
    const int wid = tid >> 6;
    const int wm = wid >> 2, wn = wid & 3;
    const int m0 = blockIdx.y * 256, n0 = blockIdx.x * 256;
    const int lrow = lane & 15, hc = lane >> 4;
    const int rowbase = ((lrow >> 1) * 128) +
                        (((((lrow & 1) << 2) | hc) ^ (lrow >> 1)) << 4);
    const int NT = GK / 64;

    auto stageR = [&](int t, int kh) {
#pragma unroll
        for (int it = 0; it < 2; ++it) {
            int sl = it * 512 + tid;              // 16B chunk id 0..1023
            int PRr = sl >> 3, ps = sl & 7;       // pair-row, phys slot
            int lsl = ps ^ (PRr & 7);             // logical slot (involution)
            int r = PRr * 2 + (lsl >> 2);         // logical row 0..255
            int cc = lsl & 3;                     // 16B col-chunk 0..3
            size_t koff = (size_t)t * 64 + kh * 32 + cc * 8;
            gload_lds16(A + (size_t)(m0 + r) * GK + koff, &sA[t & 1][kh][sl * 16]);
            gload_lds16(Bt + (size_t)(n0 + r) * GK + koff, &sB[t & 1][kh][sl * 16]);
        }
    };

    f32x4 acc[8][4] = {};
    bf16x8 af[8], bfr[4];

    auto phread = [&](int t, int kh) {
        const char* Ab = &sA[t & 1][kh][0];
        const char* Bb = &sB[t & 1][kh][0];
#pragma unroll
        for (int ni = 0; ni < 4; ++ni)
            bfr[ni] = *(const bf16x8*)(Bb + wn * 4096 + ni * 1024 + rowbase);
#pragma unroll
        for (int mi = 0; mi < 8; ++mi)
            af[mi] = *(const bf16x8*)(Ab + wm * 8192 + mi * 1024 + rowbase);
    };
    auto phmfma = [&]() {
        __builtin_amdgcn_s_barrier();
        asm volatile("s_waitcnt lgkmcnt(0)" ::: "memory");
        __builtin_amdgcn_sched_barrier(0);
        __builtin_amdgcn_s_setprio(1);
#pragma unroll
        for (int mi = 0; mi < 8; ++mi)
#pragma unroll
            for (int ni = 0; ni < 4; ++ni)
                acc[mi][ni] = __builtin_amdgcn_mfma_f32_16x16x32_bf16(af[mi], bfr[ni], acc[mi][ni], 0, 0, 0);
        __builtin_amdgcn_s_setprio(0);
    };

    // prologue: stage both halves of tile 0 (8 VMEM/thread)
    stageR(0, 0); stageR(0, 1);
    asm volatile("s_waitcnt vmcnt(4)" ::: "memory");   // own (0,0) retired
    __builtin_amdgcn_s_barrier();                      // all waves' (0,0) landed

    for (int t = 0; t < NT; ++t) {
#pragma unroll
        for (int kh = 0; kh < 2; ++kh) {
            phread(t, kh);
            if (t + 1 < NT) {
                stageR(t + 1, kh);
                asm volatile("s_waitcnt vmcnt(4)" ::: "memory");
            } else {
                asm volatile("s_waitcnt vmcnt(0)" ::: "memory");
            }
            phmfma();
        }
    }

    // epilogue
    if constexpr (MODE == 1) {
        // fused RoPE: pair element (d^1) is in adjacent lane; fp32 pre-round
        float inv4[4];
#pragma unroll
        for (int ni = 0; ni < 4; ++ni) {
            int d = ((wn & 1) * 64 + ni * 16 + lrow) & 127;
            inv4[ni] = exp2f(NL2T * (float)(d >> 1));
        }
        const bool ev = (lrow & 1) == 0;
#pragma unroll
        for (int mi = 0; mi < 8; ++mi)
#pragma unroll
            for (int ni = 0; ni < 4; ++ni)
#pragma unroll
                for (int r = 0; r < 4; ++r) {
                    int row = m0 + wm * 128 + mi * 16 + hc * 4 + r;
                    int col = n0 + wn * 64 + ni * 16 + lrow;
                    float v = acc[mi][ni][r];
                    float p = __shfl_xor(v, 1, 64);
                    float ang = (float)(row & (SEQ - 1)) * inv4[ni];
                    float sn = __sinf(ang), cs = __cosf(ang);
                    float o = v * cs + (ev ? -p * sn : p * sn);
                    ((bf16*)outp)[(size_t)row * N + col] = (bf16)(o * oscale);
                }
    } else {
#pragma unroll
        for (int mi = 0; mi < 8; ++mi)
#pragma unroll
            for (int ni = 0; ni < 4; ++ni)
#pragma unroll
                for (int r = 0; r < 4; ++r) {
                    int row = m0 + wm * 128 + mi * 16 + hc * 4 + r;
                    int col = n0 + wn * 64 + ni * 16 + lrow;
                    if constexpr (MODE == 2)
                        ((float*)outp)[(size_t)row * N + col] = acc[mi][ni][r];
                    else
                        ((bf16*)outp)[(size_t)row * N + col] = (bf16)acc[mi][ni][r];
                }
    }
}

// ---------------- flash attention, GQA, causal ----------------
// grid: 512 = b(2) * h(32) * pair(8); 8 waves x 16 q-rows = 128 q-rows/pass;
// each block runs two passes (q-tile pr and 15-pr) -> exactly 34 KV rounds each.
// Swapped QK^T (S^T). Q pre-scaled by 1/sqrt(d)*log2(e) -> exp2-domain softmax.
// Wave-uniform diag split + defer-max (THR=8).
__global__ __launch_bounds__(512, 4) void attn_fwd(const bf16* __restrict__ q,
                                                   const bf16* __restrict__ k,
                                                   const bf16* __restrict__ vt,
                                                   bf16* __restrict__ o) {
    __shared__ alignas(16) bf16 sK[2][64 * 128];   // [kv][d], XOR-swizzled source
    __shared__ alignas(16) bf16 sV[2][128 * 64];   // [d][kv], XOR-swizzled source
    __shared__ alignas(16) bf16 sP[8][16 * 64];    // per-wave P[q][kv], swizzled
    const int tid = threadIdx.x, lane = tid & 63, wid = tid >> 6;
    const int bi = blockIdx.x;
    const int pr = bi & 7;
    const int h = (bi >> 3) & 31;
    const int b = bi >> 8;
    const int kvh = h >> 2;

    const bf16* kb0 = k + (size_t)b * SEQ * (NKV * HD) + kvh * HD;
    const bf16* vb0 = vt + (size_t)(kvh * HD) * MTOT + (size_t)b * SEQ;

    auto stage = [&](int bf, int tt) {
#pragma unroll
        for (int it = 0; it < 2; ++it) {
            int slot = it * 512 + tid;
            int row = slot >> 4, s = slot & 15;
            gload_lds16(kb0 + (size_t)(tt * 64 + row) * (NKV * HD) + ((s ^ (row & 7)) * 8),
                        &sK[bf][slot * 8]);
        }
#pragma unroll
        for (int it = 0; it < 2; ++it) {
            int slot = it * 512 + tid;
            int row = slot >> 3, s = slot & 7;
            gload_lds16(vb0 + (size_t)row * MTOT + tt * 64 + ((s ^ (row & 7)) * 8),
                        &sV[bf][slot * 8]);
        }
    };

    auto pass = [&](int qt) {
        const int qb0 = qt * 128;
        const int nt = 2 * qt + 2;
        const int qw = qb0 + wid * 16;        // wave's first q row (16-aligned)
        const bf16* qp = q + ((size_t)(b * SEQ + qw + (lane & 15))) * DIM
                           + h * HD + (lane >> 4) * 8;
        bf16x8 aQ[4];
#pragma unroll
        for (int ks = 0; ks < 4; ++ks) aQ[ks] = *(const bf16x8*)(qp + ks * 32);

        f32x4 accO[8] = {};
        float m_r = -1e30f, l_r = 0.f;   // per-lane: q-col = lane&15 (uniform over hi)
        const int qglob = qw + (lane & 15);
        char* pb = (char*)&sP[wid][0];
        const int q7s = (lane & 7) << 4;
        const int hi = lane >> 4;

        stage(0, 0);
        __syncthreads();
        int cur = 0;
        for (int tt = 0; tt < nt; ++tt) {
            if (tt + 1 < nt) stage(cur ^ 1, tt + 1);
            // skip tiles fully above this wave's rows (t0 and qw both 16-aligned)
            if (tt * 64 <= qw) {
                // S^T = mfma(K, Q): frag nt2 -> kv = tt*64+nt2*16+hi*4+r, col q = lane&15
                f32x4 accS[4] = {};
#pragma unroll
                for (int nt2 = 0; nt2 < 4; ++nt2) {
                    int kr = nt2 * 16 + (lane & 15);
#pragma unroll
                    for (int ks = 0; ks < 4; ++ks) {
                        int slog = ks * 4 + hi;
                        bf16x8 bK = *(const bf16x8*)&sK[cur][kr * 128 + ((slog ^ (kr & 7)) * 8)];
                        accS[nt2] = __builtin_amdgcn_mfma_f32_16x16x32_bf16(bK, aQ[ks], accS[nt2], 0, 0, 0);
                    }
                }

                // lane-local max over 16 kv values; mask only on diagonal tiles
                const bool diag = (tt * 64 + 63 > qw);
                float mx = -1e30f;
                if (diag) {
                    const int kvb = tt * 64 + hi * 4;
#pragma unroll
                    for (int nt2 = 0; nt2 < 4; ++nt2)
#pragma unroll
                        for (int r = 0; r < 4; ++r) {
                            float v = accS[nt2][r];
                            if (kvb + nt2 * 16 + r > qglob) v = -1e30f;
                            accS[nt2][r] = v;
                            mx = fmaxf(mx, v);
                        }
                } else {
#pragma unroll
                    for (int nt2 = 0; nt2 < 4; ++nt2)
#pragma unroll
                        for (int r = 0; r < 4; ++r) mx = fmaxf(mx, accS[nt2][r]);
                }
                mx = fmaxf(mx, __shfl_xor(mx, 16, 64));
                mx = fmaxf(mx, __shfl_xor(mx, 32, 64));

                // defer-max: only rescale when tile max advances past m_r + 8
                if (!__all(mx <= m_r + 8.f)) {
                    float mn = fmaxf(m_r, mx);
                    float al = __builtin_amdgcn_exp2f(m_r - mn);
                    m_r = mn;
                    l_r *= al;
                    float al4[4];
#pragma unroll
                    for (int r = 0; r < 4; ++r) al4[r] = __shfl(al, hi * 4 + r, 64);
#pragma unroll
                    for (int d2 = 0; d2 < 8; ++d2)
#pragma unroll
                        for (int r = 0; r < 4; ++r) accO[d2][r] *= al4[r];
                }

                float rs = 0.f;
#pragma unroll
                for (int nt2 = 0; nt2 < 4; ++nt2)
#pragma unroll
                    for (int r = 0; r < 4; ++r) {
                        float p = __builtin_amdgcn_exp2f(accS[nt2][r] - m_r);
                        accS[nt2][r] = p;
                        rs += p;
                    }
                rs += __shfl_xor(rs, 16, 64);
                rs += __shfl_xor(rs, 32, 64);
                l_r += rs;

                // P-write: lane holds 4 contiguous kv per frag -> b64 stores
#pragma unroll
                for (int nt2 = 0; nt2 < 4; ++nt2) {
                    bf16x4 pv;
                    pv[0] = (bf16)accS[nt2][0]; pv[1] = (bf16)accS[nt2][1];
                    pv[2] = (bf16)accS[nt2][2]; pv[3] = (bf16)accS[nt2][3];
                    *(bf16x4*)(pb + (lane & 15) * 128 + ((nt2 * 32 + hi * 8) ^ q7s)) = pv;
                }

                // PV: O[16 x 128] += P[16 x 64] * V[64 x 128]
                bf16x8 aP[2];
#pragma unroll
                for (int kk = 0; kk < 2; ++kk)
                    aP[kk] = *(const bf16x8*)(pb + (lane & 15) * 128 + ((kk * 64 + hi * 16) ^ q7s));
#pragma unroll
                for (int d2 = 0; d2 < 8; ++d2) {
#pragma unroll
                    for (int kk = 0; kk < 2; ++kk) {
                        int dv = d2 * 16 + (lane & 15);
                        int phys = (kk * 4 + hi) ^ (dv & 7);
                        bf16x8 bV = *(const bf16x8*)&sV[cur][dv * 64 + phys * 8];
                        accO[d2] = __builtin_amdgcn_mfma_f32_16x16x32_bf16(aP[kk], bV, accO[d2], 0, 0, 0);
                    }
                }
            }
            __syncthreads();
            cur ^= 1;
        }

        // epilogue: normalize + store bf16 (accO q-row for reg r = hi*4+r)
        float linv[4];
#pragma unroll
        for (int r = 0; r < 4; ++r) linv[r] = 1.f / __shfl(l_r, hi * 4 + r, 64);
        size_t orow = (size_t)(b * SEQ + qb0 + wid * 16 + hi * 4) * DIM
                    + h * HD + (lane & 15);
#pragma unroll
        for (int d2 = 0; d2 < 8; ++d2)
#pragma unroll
            for (int r = 0; r < 4; ++r)
                o[orow + (size_t)r * DIM + d2 * 16] = (bf16)(accO[d2][r] * linv[r]);
    };

    pass(pr);
    pass(15 - pr);
}

// ---------------- launch ----------------
extern "C" void kernel_launch(void* const* d_in, const int* in_sizes, int n_in,
                              void* d_out, int out_size, void* d_ws, size_t ws_size,
                              hipStream_t stream) {
    const float* x  = (const float*)d_in[0];
    const float* wq = (const float*)d_in[1];
    const float* wk = (const float*)d_in[2];
    const float* wv = (const float*)d_in[3];
    const float* wo = (const float*)d_in[4];
    float* out = (float*)d_out;

    char* ws = (char*)d_ws;
    size_t off = 0;
    bf16* xb  = (bf16*)(ws + off); off += (size_t)MTOT * DIM * 2;   // 32 MiB (reused as attn_out)
    bf16* wqt = (bf16*)(ws + off); off += (size_t)DIM * DIM * 2;    // 32 MiB (reused as wo_t)
    bf16* wkt = (bf16*)(ws + off); off += (size_t)1024 * DIM * 2;   // 8 MiB
    bf16* wvt = (bf16*)(ws + off); off += (size_t)1024 * DIM * 2;   // 8 MiB
    bf16* qb  = (bf16*)(ws + off); off += (size_t)MTOT * DIM * 2;   // 32 MiB
    bf16* kb  = (bf16*)(ws + off); off += (size_t)MTOT * 1024 * 2;  // 8 MiB
    bf16* vtb = (bf16*)(ws + off); off += (size_t)MTOT * 1024 * 2;  // 8 MiB  V^T [1024][4096]
    bf16* ao = xb;  // attention output reuses x_bf16

    // 1/sqrt(HD) * log2(e): folds softmax scale + exp->exp2 conversion into Q
    const float SCALE2 = 0.08838834764831845f * 1.44269504088896340f;

    // fused prep: x convert (8192) + wq (4096) + wk (1024) + wv (1024)
    prep<<<8192 + 4096 + 1024 + 1024, 256, 0, stream>>>(x, wq, wk, wv, xb, wqt, wkt, wvt);

    // Q proj with fused RoPE+scale: 4096^3 on the 256^2 pipelined kernel
    gemm8<1><<<dim3(DIM / 256, MTOT / 256), 512, 0, stream>>>(xb, wqt, qb, DIM, SCALE2);

    // wo transpose (4096 blocks, runs first & overlaps) + K proj (RoPE fused)
    // + V^T proj, all in one 4608-block launch. wqt is free after Q-proj.
    gemm_kv<<<4096 + 512, 256, 0, stream>>>(xb, wkt, wvt, kb, vtb, wo, wqt);

    attn_fwd<<<BATCH * NH * 8, 512, 0, stream>>>(qb, kb, vtb, ao);

    // out proj: fp32 output on the 256^2 kernel (wqt now holds wo^T)
    gemm8<2><<<dim3(DIM / 256, MTOT / 256), 512, 0, stream>>>(ao, wqt, out, DIM, 1.0f);
}

// Round 15
// 523.093 us; speedup vs baseline: 1.0000x; 1.0000x over previous
//
#include <hip/hip_runtime.h>

#define DIM 4096
#define HD 128
#define NH 32
#define NKV 8
#define SEQ 2048
#define BATCH 2
#define MTOT (BATCH*SEQ)   // 4096 rows total
#define GK DIM             // K dim of every GEMM

typedef __bf16 bf16;
typedef __bf16 bf16x4 __attribute__((ext_vector_type(4)));
typedef __bf16 bf16x8 __attribute__((ext_vector_type(8)));
typedef float f32x4 __attribute__((ext_vector_type(4)));

#define NL2T (-13.287712379549449f / 64.f)   // -log2(10000)/(HD/2)

__device__ __forceinline__ void gload_lds16(const void* g, void* l) {
    __builtin_amdgcn_global_load_lds(
        (const __attribute__((address_space(1))) void*)g,
        (__attribute__((address_space(3))) void*)l, 16, 0, 0);
}

// ---------------- 64x64 transpose-convert tile: fp32 [K][N] -> bf16 [N][K] --
__device__ __forceinline__ void tconv64_tile(const float* __restrict__ in,
                                             bf16* __restrict__ out,
                                             int N, int K, int bx, int by,
                                             float t[64][65], int tid) {
    int rr = tid >> 4;              // 0..15
    int cc = (tid & 15) * 4;        // 0..60
    const float* ip = in + ((size_t)(by * 64 + rr)) * N + bx * 64 + cc;
#pragma unroll
    for (int p = 0; p < 4; ++p) {
        float4 v = *(const float4*)(ip + (size_t)p * 16 * N);
        t[rr + p * 16][cc + 0] = v.x;
        t[rr + p * 16][cc + 1] = v.y;
        t[rr + p * 16][cc + 2] = v.z;
        t[rr + p * 16][cc + 3] = v.w;
    }
    __syncthreads();
#pragma unroll
    for (int p = 0; p < 4; ++p) {
        int n = rr + p * 16;
        bf16x4 o;
#pragma unroll
        for (int j = 0; j < 4; ++j) o[j] = (bf16)t[cc + j][n];
        *(bf16x4*)(out + (size_t)(bx * 64 + n) * K + by * 64 + cc) = o;
    }
}

// ---------------- fused prep: x->bf16 convert + wq/wk/wv transpose-convert --
__global__ __launch_bounds__(256) void prep(const float* __restrict__ x,
                                            const float* __restrict__ wq,
                                            const float* __restrict__ wk,
                                            const float* __restrict__ wv,
                                            bf16* __restrict__ xb,
                                            bf16* __restrict__ wqt,
                                            bf16* __restrict__ wkt,
                                            bf16* __restrict__ wvt) {
    __shared__ float t[64][65];
    const int bid = blockIdx.x, tid = threadIdx.x;
    if (bid < 8192) {                       // x convert: 8192*256*8 = MTOT*DIM
        int i = bid * 256 + tid;
        const float4* p = (const float4*)(x + (size_t)i * 8);
        float4 a = p[0], b = p[1];
        bf16x8 v;
        v[0]=(bf16)a.x; v[1]=(bf16)a.y; v[2]=(bf16)a.z; v[3]=(bf16)a.w;
        v[4]=(bf16)b.x; v[5]=(bf16)b.y; v[6]=(bf16)b.z; v[7]=(bf16)b.w;
        *(bf16x8*)(xb + (size_t)i * 8) = v;
    } else if (bid < 8192 + 4096) {         // wq: 64x64 tiles
        int b2 = bid - 8192;
        tconv64_tile(wq, wqt, DIM, DIM, b2 & 63, b2 >> 6, t, tid);
    } else if (bid < 8192 + 4096 + 1024) {  // wk
        int b2 = bid - (8192 + 4096);
        tconv64_tile(wk, wkt, 1024, DIM, b2 & 15, b2 >> 4, t, tid);
    } else {                                // wv
        int b2 = bid - (8192 + 4096 + 1024);
        tconv64_tile(wv, wvt, 1024, DIM, b2 & 15, b2 >> 4, t, tid);
    }
}

// ---------------- merged wo-transpose + K-proj + V^T-proj (one launch) -----
// blocks 0..4095: wo [K][N] -> wo^T bf16 into wqt (wqt free: Q-proj done).
//   tconv FIRST so these short memory-bound blocks fill CUs and the gemm
//   blocks backfill to run concurrently (gemm-first would serialize the tail).
// blocks 4096..4351: kb = xb * wkt^T (RoPE fused in epilogue).
// blocks 4352..4607: vtb = wvt * xb^T.
// __sinf/__cosf ONLY (sincosf's OCML call spilled acc to scratch: R11).
__global__ __launch_bounds__(256, 2) void gemm_kv(const bf16* __restrict__ xb,
                                                  const bf16* __restrict__ wkt,
                                                  const bf16* __restrict__ wvt,
                                                  bf16* __restrict__ kb,
                                                  bf16* __restrict__ vtb,
                                                  const float* __restrict__ wo,
                                                  bf16* __restrict__ wot) {
    __shared__ alignas(16) bf16 sA[2][128 * 32];
    __shared__ alignas(16) bf16 sB[2][128 * 32];
    __shared__ float t[64][65];
    const int tid = threadIdx.x;
    const int bid = blockIdx.x;

    if (bid < 4096) {                       // wo transpose-convert
        tconv64_tile(wo, wot, DIM, DIM, bid & 63, bid >> 6, t, tid);
        return;
    }

    const int g = bid - 4096;
    const int lane = tid & 63, wid = tid >> 6;
    const int wm = wid >> 1, wn = wid & 1;

    const bf16 *A, *Bt;
    bf16* out0;
    int N, m0, n0;
    const bool isK = (g < 256);
    if (isK) {
        A = xb; Bt = wkt; out0 = kb; N = 1024;
        m0 = (g >> 3) * 128; n0 = (g & 7) * 128;
    } else {
        int b2 = g - 256;
        A = wvt; Bt = xb; out0 = vtb; N = MTOT;
        m0 = (b2 >> 5) * 128; n0 = (b2 & 31) * 128;
    }

    auto stage = [&](int buf, int kt) {
#pragma unroll
        for (int it = 0; it < 2; ++it) {
            int slot = it * 256 + tid;
            int row = slot >> 2, s = slot & 3;
            gload_lds16(A + (size_t)(m0 + row) * GK + kt * 32 + s * 8, &sA[buf][slot * 8]);
            gload_lds16(Bt + (size_t)(n0 + row) * GK + kt * 32 + s * 8, &sB[buf][slot * 8]);
        }
    };

    f32x4 acc[4][4] = {};
    stage(0, 0);
    __syncthreads();
    int cur = 0;
    for (int kt = 0; kt < GK / 32; ++kt) {
        if (kt + 1 < GK / 32) stage(cur ^ 1, kt + 1);
        bf16x8 bF[4], aF[4];
#pragma unroll
        for (int i = 0; i < 4; ++i)
            bF[i] = *(const bf16x8*)&sB[cur][(wn * 64 + i * 16 + (lane & 15)) * 32 + (lane >> 4) * 8];
#pragma unroll
        for (int i = 0; i < 4; ++i)
            aF[i] = *(const bf16x8*)&sA[cur][(wm * 64 + i * 16 + (lane & 15)) * 32 + (lane >> 4) * 8];
#pragma unroll
        for (int mi = 0; mi < 4; ++mi)
#pragma unroll
            for (int ni = 0; ni < 4; ++ni)
                acc[mi][ni] = __builtin_amdgcn_mfma_f32_16x16x32_bf16(aF[mi], bF[ni], acc[mi][ni], 0, 0, 0);
        __syncthreads();
        cur ^= 1;
    }

    const int lrow = lane & 15;
    if (isK) {
        // fused RoPE epilogue: d = col&127, pair in lane^1, pos = row&2047
        float inv4[4];
#pragma unroll
        for (int ni = 0; ni < 4; ++ni) {
            int d = (wn * 64 + ni * 16 + lrow) & 127;
            inv4[ni] = exp2f(NL2T * (float)(d >> 1));
        }
        const bool ev = (lrow & 1) == 0;
#pragma unroll
        for (int mi = 0; mi < 4; ++mi)
#pragma unroll
            for (int ni = 0; ni < 4; ++ni)
#pragma unroll
                for (int r = 0; r < 4; ++r) {
                    int row = m0 + wm * 64 + mi * 16 + (lane >> 4) * 4 + r;
                    int col = n0 + wn * 64 + ni * 16 + lrow;
                    float v = acc[mi][ni][r];
                    float p = __shfl_xor(v, 1, 64);
                    float ang = (float)(row & (SEQ - 1)) * inv4[ni];
                    float sn = __sinf(ang), cs = __cosf(ang);
                    float o = v * cs + (ev ? -p * sn : p * sn);
                    out0[(size_t)row * N + col] = (bf16)o;
                }
    } else {
#pragma unroll
        for (int mi = 0; mi < 4; ++mi)
#pragma unroll
            for (int ni = 0; ni < 4; ++ni)
#pragma unroll
                for (int r = 0; r < 4; ++r) {
                    int row = m0 + wm * 64 + mi * 16 + (lane >> 4) * 4 + r;
                    int col = n0 + wn * 64 + ni * 16 + lrow;
                    out0[(size_t)row * N + col] = (bf16)acc[mi][ni][r];
                }
    }
}

// ---------------- 256x256 deep-pipelined GEMM (R7 schedule, best measured) --
// Phase p (one 32-wide K-half): [12 ds_read B-first][stage next region]
// [vmcnt(4)][s_barrier][lgkmcnt(0)+sched_barrier][setprio + 32 MFMA].
// MODE 0: bf16 out. MODE 1: bf16 out + fused RoPE (oscale folded). MODE 2: f32.
template <int MODE>
__global__ __launch_bounds__(512, 2) void gemm8(const bf16* __restrict__ A,
                                                const bf16* __restrict__ Bt,
                                                void* __restrict__ outp, int N,
                                                float oscale) {
    __shared__ alignas(16) char sA[2][2][16384];
    __shared__ alignas(16) char sB[2][2][16384];
    const int tid = threadIdx.x, lane = tid & 63;
    const int wid = tid >> 6;
    const int wm = wid >> 2, wn = wid & 3;
    const int m0 = blockIdx.y * 256, n0 = blockIdx.x * 256;
    const int lrow = lane & 15, hc = lane >> 4;
    const int rowbase = ((lrow >> 1) * 128) +
                        (((((lrow & 1) << 2) | hc) ^ (lrow >> 1)) << 4);
    const int NT = GK / 64;

    auto stageR = [&](int t, int kh) {
#pragma unroll
        for (int it = 0; it < 2; ++it) {
            int sl = it * 512 + tid;              // 16B chunk id 0..1023
            int PRr = sl >> 3, ps = sl & 7;       // pair-row, phys slot
            int lsl = ps ^ (PRr & 7);             // logical slot (involution)
            int r = PRr * 2 + (lsl >> 2);         // logical row 0..255
            int cc = lsl & 3;                     // 16B col-chunk 0..3
            size_t koff = (size_t)t * 64 + kh * 32 + cc * 8;
            gload_lds16(A + (size_t)(m0 + r) * GK + koff, &sA[t & 1][kh][sl * 16]);
            gload_lds16(Bt + (size_t)(n0 + r) * GK + koff, &sB[t & 1][kh][sl * 16]);
        }
    };

    f32x4 acc[8][4] = {};
    bf16x8 af[8], bfr[4];

    auto phread = [&](int t, int kh) {
        const char* Ab = &sA[t & 1][kh][0];
        const char* Bb = &sB[t & 1][kh][0];
#pragma unroll
        for (int ni = 0; ni < 4; ++ni)
            bfr[ni] = *(const bf16x8*)(Bb + wn * 4096 + ni * 1024 + rowbase);
#pragma unroll
        for (int mi = 0; mi < 8; ++mi)
            af[mi] = *(const bf16x8*)(Ab + wm * 8192 + mi * 1024 + rowbase);
    };
    auto phmfma = [&]() {
        __builtin_amdgcn_s_barrier();
        asm volatile("s_waitcnt lgkmcnt(0)" ::: "memory");
        __builtin_amdgcn_sched_barrier(0);
        __builtin_amdgcn_s_setprio(1);
#pragma unroll
        for (int mi = 0; mi < 8; ++mi)
#pragma unroll
            for (int ni = 0; ni < 4; ++ni)
                acc[mi][ni] = __builtin_amdgcn_mfma_f32_16x16x32_bf16(af[mi], bfr[ni], acc[mi][ni], 0, 0, 0);
        __builtin_amdgcn_s_setprio(0);
    };

    // prologue: stage both halves of tile 0 (8 VMEM/thread)
    stageR(0, 0); stageR(0, 1);
    asm volatile("s_waitcnt vmcnt(4)" ::: "memory");   // own (0,0) retired
    __builtin_amdgcn_s_barrier();                      // all waves' (0,0) landed

    for (int t = 0; t < NT; ++t) {
#pragma unroll
        for (int kh = 0; kh < 2; ++kh) {
            phread(t, kh);
            if (t + 1 < NT) {
                stageR(t + 1, kh);
                asm volatile("s_waitcnt vmcnt(4)" ::: "memory");
            } else {
                asm volatile("s_waitcnt vmcnt(0)" ::: "memory");
            }
            phmfma();
        }
    }

    // epilogue
    if constexpr (MODE == 1) {
        // fused RoPE: pair element (d^1) is in adjacent lane; fp32 pre-round
        float inv4[4];
#pragma unroll
        for (int ni = 0; ni < 4; ++ni) {
            int d = ((wn & 1) * 64 + ni * 16 + lrow) & 127;
            inv4[ni] = exp2f(NL2T * (float)(d >> 1));
        }
        const bool ev = (lrow & 1) == 0;
#pragma unroll
        for (int mi = 0; mi < 8; ++mi)
#pragma unroll
            for (int ni = 0; ni < 4; ++ni)
#pragma unroll
                for (int r = 0; r < 4; ++r) {
                    int row = m0 + wm * 128 + mi * 16 + hc * 4 + r;
                    int col = n0 + wn * 64 + ni * 16 + lrow;
                    float v = acc[mi][ni][r];
                    float p = __shfl_xor(v, 1, 64);
                    float ang = (float)(row & (SEQ - 1)) * inv4[ni];
                    float sn = __sinf(ang), cs = __cosf(ang);
                    float o = v * cs + (ev ? -p * sn : p * sn);
                    ((bf16*)outp)[(size_t)row * N + col] = (bf16)(o * oscale);
                }
    } else {
#pragma unroll
        for (int mi = 0; mi < 8; ++mi)
#pragma unroll
            for (int ni = 0; ni < 4; ++ni)
#pragma unroll
                for (int r = 0; r < 4; ++r) {
                    int row = m0 + wm * 128 + mi * 16 + hc * 4 + r;
                    int col = n0 + wn * 64 + ni * 16 + lrow;
                    if constexpr (MODE == 2)
                        ((float*)outp)[(size_t)row * N + col] = acc[mi][ni][r];
                    else
                        ((bf16*)outp)[(size_t)row * N + col] = (bf16)acc[mi][ni][r];
                }
    }
}

// ---------------- flash attention, GQA, causal ----------------
// grid: 512 = b(2) * h(32) * pair(8); 8 waves x 16 q-rows = 128 q-rows/pass;
// each block runs two passes (q-tile pr and 15-pr) -> exactly 34 KV rounds each.
// Swapped QK^T (S^T). Q pre-scaled by 1/sqrt(d)*log2(e) -> exp2-domain softmax.
// Wave-uniform diag split + defer-max (THR=8).
__global__ __launch_bounds__(512, 4) void attn_fwd(const bf16* __restrict__ q,
                                                   const bf16* __restrict__ k,
                                                   const bf16* __restrict__ vt,
                                                   bf16* __restrict__ o) {
    __shared__ alignas(16) bf16 sK[2][64 * 128];   // [kv][d], XOR-swizzled source
    __shared__ alignas(16) bf16 sV[2][128 * 64];   // [d][kv], XOR-swizzled source
    __shared__ alignas(16) bf16 sP[8][16 * 64];    // per-wave P[q][kv], swizzled
    const int tid = threadIdx.x, lane = tid & 63, wid = tid >> 6;
    const int bi = blockIdx.x;
    const int pr = bi & 7;
    const int h = (bi >> 3) & 31;
    const int b = bi >> 8;
    const int kvh = h >> 2;

    const bf16* kb0 = k + (size_t)b * SEQ * (NKV * HD) + kvh * HD;
    const bf16* vb0 = vt + (size_t)(kvh * HD) * MTOT + (size_t)b * SEQ;

    auto stage = [&](int bf, int tt) {
#pragma unroll
        for (int it = 0; it < 2; ++it) {
            int slot = it * 512 + tid;
            int row = slot >> 4, s = slot & 15;
            gload_lds16(kb0 + (size_t)(tt * 64 + row) * (NKV * HD) + ((s ^ (row & 7)) * 8),
                        &sK[bf][slot * 8]);
        }
#pragma unroll
        for (int it = 0; it < 2; ++it) {
            int slot = it * 512 + tid;
            int row = slot >> 3, s = slot & 7;
            gload_lds16(vb0 + (size_t)row * MTOT + tt * 64 + ((s ^ (row & 7)) * 8),
                        &sV[bf][slot * 8]);
        }
    };

    auto pass = [&](int qt) {
        const int qb0 = qt * 128;
        const int nt = 2 * qt + 2;
        const int qw = qb0 + wid * 16;        // wave's first q row (16-aligned)
        const bf16* qp = q + ((size_t)(b * SEQ + qw + (lane & 15))) * DIM
                           + h * HD + (lane >> 4) * 8;
        bf16x8 aQ[4];
#pragma unroll
        for (int ks = 0; ks < 4; ++ks) aQ[ks] = *(const bf16x8*)(qp + ks * 32);

        f32x4 accO[8] = {};
        float m_r = -1e30f, l_r = 0.f;   // per-lane: q-col = lane&15 (uniform over hi)
        const int qglob = qw + (lane & 15);
        char* pb = (char*)&sP[wid][0];
        const int q7s = (lane & 7) << 4;
        const int hi = lane >> 4;

        stage(0, 0);
        __syncthreads();
        int cur = 0;
        for (int tt = 0; tt < nt; ++tt) {
            if (tt + 1 < nt) stage(cur ^ 1, tt + 1);
            // skip tiles fully above this wave's rows (t0 and qw both 16-aligned)
            if (tt * 64 <= qw) {
                // S^T = mfma(K, Q): frag nt2 -> kv = tt*64+nt2*16+hi*4+r, col q = lane&15
                f32x4 accS[4] = {};
#pragma unroll
                for (int nt2 = 0; nt2 < 4; ++nt2) {
                    int kr = nt2 * 16 + (lane & 15);
#pragma unroll
                    for (int ks = 0; ks < 4; ++ks) {
                        int slog = ks * 4 + hi;
                        bf16x8 bK = *(const bf16x8*)&sK[cur][kr * 128 + ((slog ^ (kr & 7)) * 8)];
                        accS[nt2] = __builtin_amdgcn_mfma_f32_16x16x32_bf16(bK, aQ[ks], accS[nt2], 0, 0, 0);
                    }
                }

                // lane-local max over 16 kv values; mask only on diagonal tiles
                const bool diag = (tt * 64 + 63 > qw);
                float mx = -1e30f;
                if (diag) {
                    const int kvb = tt * 64 + hi * 4;
#pragma unroll
                    for (int nt2 = 0; nt2 < 4; ++nt2)
#pragma unroll
                        for (int r = 0; r < 4; ++r) {
                            float v = accS[nt2][r];
                            if (kvb + nt2 * 16 + r > qglob) v = -1e30f;
                            accS[nt2][r] = v;
                            mx = fmaxf(mx, v);
                        }
                } else {
#pragma unroll
                    for (int nt2 = 0; nt2 < 4; ++nt2)
#pragma unroll
                        for (int r = 0; r < 4; ++r) mx = fmaxf(mx, accS[nt2][r]);
                }
                mx = fmaxf(mx, __shfl_xor(mx, 16, 64));
                mx = fmaxf(mx, __shfl_xor(mx, 32, 64));

                // defer-max: only rescale when tile max advances past m_r + 8
                if (!__all(mx <= m_r + 8.f)) {
                    float mn = fmaxf(m_r, mx);
                    float al = __builtin_amdgcn_exp2f(m_r - mn);
                    m_r = mn;
                    l_r *= al;
                    float al4[4];
#pragma unroll
                    for (int r = 0; r < 4; ++r) al4[r] = __shfl(al, hi * 4 + r, 64);
#pragma unroll
                    for (int d2 = 0; d2 < 8; ++d2)
#pragma unroll
                        for (int r = 0; r < 4; ++r) accO[d2][r] *= al4[r];
                }

                float rs = 0.f;
#pragma unroll
                for (int nt2 = 0; nt2 < 4; ++nt2)
#pragma unroll
                    for (int r = 0; r < 4; ++r) {
                        float p = __builtin_amdgcn_exp2f(accS[nt2][r] - m_r);
                        accS[nt2][r] = p;
                        rs += p;
                    }
                rs += __shfl_xor(rs, 16, 64);
                rs += __shfl_xor(rs, 32, 64);
                l_r += rs;

                // P-write: lane holds 4 contiguous kv per frag -> b64 stores
#pragma unroll
                for (int nt2 = 0; nt2 < 4; ++nt2) {
                    bf16x4 pv;
                    pv[0] = (bf16)accS[nt2][0]; pv[1] = (bf16)accS[nt2][1];
                    pv[2] = (bf16)accS[nt2][2]; pv[3] = (bf16)accS[nt2][3];
                    *(bf16x4*)(pb + (lane & 15) * 128 + ((nt2 * 32 + hi * 8) ^ q7s)) = pv;
                }

                // PV: O[16 x 128] += P[16 x 64] * V[64 x 128]
                bf16x8 aP[2];
#pragma unroll
                for (int kk = 0; kk < 2; ++kk)
                    aP[kk] = *(const bf16x8*)(pb + (lane & 15) * 128 + ((kk * 64 + hi * 16) ^ q7s));
#pragma unroll
                for (int d2 = 0; d2 < 8; ++d2) {
#pragma unroll
                    for (int kk = 0; kk < 2; ++kk) {
                        int dv = d2 * 16 + (lane & 15);
                        int phys = (kk * 4 + hi) ^ (dv & 7);
                        bf16x8 bV = *(const bf16x8*)&sV[cur][dv * 64 + phys * 8];
                        accO[d2] = __builtin_amdgcn_mfma_f32_16x16x32_bf16(aP[kk], bV, accO[d2], 0, 0, 0);
                    }
                }
            }
            __syncthreads();
            cur ^= 1;
        }

        // epilogue: normalize + store bf16 (accO q-row for reg r = hi*4+r)
        float linv[4];
#pragma unroll
        for (int r = 0; r < 4; ++r) linv[r] = 1.f / __shfl(l_r, hi * 4 + r, 64);
        size_t orow = (size_t)(b * SEQ + qb0 + wid * 16 + hi * 4) * DIM
                    + h * HD + (lane & 15);
#pragma unroll
        for (int d2 = 0; d2 < 8; ++d2)
#pragma unroll
            for (int r = 0; r < 4; ++r)
                o[orow + (size_t)r * DIM + d2 * 16] = (bf16)(accO[d2][r] * linv[r]);
    };

    pass(pr);
    pass(15 - pr);
}

// ---------------- launch ----------------
extern "C" void kernel_launch(void* const* d_in, const int* in_sizes, int n_in,
                              void* d_out, int out_size, void* d_ws, size_t ws_size,
                              hipStream_t stream) {
    const float* x  = (const float*)d_in[0];
    const float* wq = (const float*)d_in[1];
    const float* wk = (const float*)d_in[2];
    const float* wv = (const float*)d_in[3];
    const float* wo = (const float*)d_in[4];
    float* out = (float*)d_out;

    char* ws = (char*)d_ws;
    size_t off = 0;
    bf16* xb  = (bf16*)(ws + off); off += (size_t)MTOT * DIM * 2;   // 32 MiB (reused as attn_out)
    bf16* wqt = (bf16*)(ws + off); off += (size_t)DIM * DIM * 2;    // 32 MiB (reused as wo_t)
    bf16* wkt = (bf16*)(ws + off); off += (size_t)1024 * DIM * 2;   // 8 MiB
    bf16* wvt = (bf16*)(ws + off); off += (size_t)1024 * DIM * 2;   // 8 MiB
    bf16* qb  = (bf16*)(ws + off); off += (size_t)MTOT * DIM * 2;   // 32 MiB
    bf16* kb  = (bf16*)(ws + off); off += (size_t)MTOT * 1024 * 2;  // 8 MiB
    bf16* vtb = (bf16*)(ws + off); off += (size_t)MTOT * 1024 * 2;  // 8 MiB  V^T [1024][4096]
    bf16* ao = xb;  // attention output reuses x_bf16

    // 1/sqrt(HD) * log2(e): folds softmax scale + exp->exp2 conversion into Q
    const float SCALE2 = 0.08838834764831845f * 1.44269504088896340f;

    // fused prep: x convert (8192) + wq (4096) + wk (1024) + wv (1024)
    prep<<<8192 + 4096 + 1024 + 1024, 256, 0, stream>>>(x, wq, wk, wv, xb, wqt, wkt, wvt);

    // Q proj with fused RoPE+scale: 4096^3 on the 256^2 pipelined kernel
    gemm8<1><<<dim3(DIM / 256, MTOT / 256), 512, 0, stream>>>(xb, wqt, qb, DIM, SCALE2);

    // wo transpose (4096 blocks, runs first & overlaps) + K proj (RoPE fused)
    // + V^T proj, all in one 4608-block launch. wqt is free after Q-proj.
    gemm_kv<<<4096 + 512, 256, 0, stream>>>(xb, wkt, wvt, kb, vtb, wo, wqt);

    attn_fwd<<<BATCH * NH * 8, 512, 0, stream>>>(qb, kb, vtb, ao);

    // out proj: fp32 output on the 256^2 kernel (wqt now holds wo^T)
    gemm8<2><<<dim3(DIM / 256, MTOT / 256), 512, 0, stream>>>(ao, wqt, out, DIM, 1.0f);
}

// Round 16
// 508.041 us; speedup vs baseline: 1.0296x; 1.0296x over previous
//
#include <hip/hip_runtime.h>

#define DIM 4096
#define HD 128
#define NH 32
#define NKV 8
#define SEQ 2048
#define BATCH 2
#define MTOT (BATCH*SEQ)   // 4096 rows total
#define GK DIM             // K dim of every GEMM

typedef __bf16 bf16;
typedef __bf16 bf16x4 __attribute__((ext_vector_type(4)));
typedef __bf16 bf16x8 __attribute__((ext_vector_type(8)));
typedef float f32x4 __attribute__((ext_vector_type(4)));

#define NL2T (-13.287712379549449f / 64.f)   // -log2(10000)/(HD/2)

__device__ __forceinline__ void gload_lds16(const void* g, void* l) {
    __builtin_amdgcn_global_load_lds(
        (const __attribute__((address_space(1))) void*)g,
        (__attribute__((address_space(3))) void*)l, 16, 0, 0);
}

// ---------------- 64x64 transpose-convert tile: fp32 [K][N] -> bf16 [N][K] --
__device__ __forceinline__ void tconv64_tile(const float* __restrict__ in,
                                             bf16* __restrict__ out,
                                             int N, int K, int bx, int by,
                                             float t[64][65], int tid) {
    int rr = tid >> 4;              // 0..15
    int cc = (tid & 15) * 4;        // 0..60
    const float* ip = in + ((size_t)(by * 64 + rr)) * N + bx * 64 + cc;
#pragma unroll
    for (int p = 0; p < 4; ++p) {
        float4 v = *(const float4*)(ip + (size_t)p * 16 * N);
        t[rr + p * 16][cc + 0] = v.x;
        t[rr + p * 16][cc + 1] = v.y;
        t[rr + p * 16][cc + 2] = v.z;
        t[rr + p * 16][cc + 3] = v.w;
    }
    __syncthreads();
#pragma unroll
    for (int p = 0; p < 4; ++p) {
        int n = rr + p * 16;
        bf16x4 o;
#pragma unroll
        for (int j = 0; j < 4; ++j) o[j] = (bf16)t[cc + j][n];
        *(bf16x4*)(out + (size_t)(bx * 64 + n) * K + by * 64 + cc) = o;
    }
}

// ---------------- fused prep: x->bf16 convert + wq/wk/wv transpose-convert --
__global__ __launch_bounds__(256) void prep(const float* __restrict__ x,
                                            const float* __restrict__ wq,
                                            const float* __restrict__ wk,
                                            const float* __restrict__ wv,
                                            bf16* __restrict__ xb,
                                            bf16* __restrict__ wqt,
                                            bf16* __restrict__ wkt,
                                            bf16* __restrict__ wvt) {
    __shared__ float t[64][65];
    const int bid = blockIdx.x, tid = threadIdx.x;
    if (bid < 8192) {                       // x convert: 8192*256*8 = MTOT*DIM
        int i = bid * 256 + tid;
        const float4* p = (const float4*)(x + (size_t)i * 8);
        float4 a = p[0], b = p[1];
        bf16x8 v;
        v[0]=(bf16)a.x; v[1]=(bf16)a.y; v[2]=(bf16)a.z; v[3]=(bf16)a.w;
        v[4]=(bf16)b.x; v[5]=(bf16)b.y; v[6]=(bf16)b.z; v[7]=(bf16)b.w;
        *(bf16x8*)(xb + (size_t)i * 8) = v;
    } else if (bid < 8192 + 4096) {         // wq: 64x64 tiles
        int b2 = bid - 8192;
        tconv64_tile(wq, wqt, DIM, DIM, b2 & 63, b2 >> 6, t, tid);
    } else if (bid < 8192 + 4096 + 1024) {  // wk
        int b2 = bid - (8192 + 4096);
        tconv64_tile(wk, wkt, 1024, DIM, b2 & 15, b2 >> 4, t, tid);
    } else {                                // wv
        int b2 = bid - (8192 + 4096 + 1024);
        tconv64_tile(wv, wvt, 1024, DIM, b2 & 15, b2 >> 4, t, tid);
    }
}

// ---------------- standalone transpose-convert (wo, after Q-proj) ----------
// Kept SEPARATE from gemm_kv: R15 fusion shared the worst-case LDS budget and
// dropped tconv occupancy 9->3 blocks/CU (-14 µs regression).
__global__ __launch_bounds__(256) void tconv64(const float* __restrict__ in,
                                               bf16* __restrict__ out, int N, int K) {
    __shared__ float t[64][65];
    tconv64_tile(in, out, N, K, blockIdx.x, blockIdx.y, t, threadIdx.x);
}

// ---------------- merged K-proj + V^T-proj (one 512-block launch) ----------
// K half: RoPE fused in epilogue. __sinf/__cosf ONLY (sincosf's OCML call
// spilled acc to scratch: R11). launch_bounds(256,2) pins the budget.
__global__ __launch_bounds__(256, 2) void gemm_kv(const bf16* __restrict__ xb,
                                                  const bf16* __restrict__ wkt,
                                                  const bf16* __restrict__ wvt,
                                                  bf16* __restrict__ kb,
                                                  bf16* __restrict__ vtb) {
    __shared__ alignas(16) bf16 sA[2][128 * 32];
    __shared__ alignas(16) bf16 sB[2][128 * 32];
    const int tid = threadIdx.x;
    const int lane = tid & 63, wid = tid >> 6;
    const int wm = wid >> 1, wn = wid & 1;

    const bf16 *A, *Bt;
    bf16* out0;
    int N, m0, n0;
    const int bid = blockIdx.x;
    const bool isK = (bid < 256);
    if (isK) {
        A = xb; Bt = wkt; out0 = kb; N = 1024;
        m0 = (bid >> 3) * 128; n0 = (bid & 7) * 128;
    } else {
        int b2 = bid - 256;
        A = wvt; Bt = xb; out0 = vtb; N = MTOT;
        m0 = (b2 >> 5) * 128; n0 = (b2 & 31) * 128;
    }

    auto stage = [&](int buf, int kt) {
#pragma unroll
        for (int it = 0; it < 2; ++it) {
            int slot = it * 256 + tid;
            int row = slot >> 2, s = slot & 3;
            gload_lds16(A + (size_t)(m0 + row) * GK + kt * 32 + s * 8, &sA[buf][slot * 8]);
            gload_lds16(Bt + (size_t)(n0 + row) * GK + kt * 32 + s * 8, &sB[buf][slot * 8]);
        }
    };

    f32x4 acc[4][4] = {};
    stage(0, 0);
    __syncthreads();
    int cur = 0;
    for (int kt = 0; kt < GK / 32; ++kt) {
        if (kt + 1 < GK / 32) stage(cur ^ 1, kt + 1);
        bf16x8 bF[4], aF[4];
#pragma unroll
        for (int i = 0; i < 4; ++i)
            bF[i] = *(const bf16x8*)&sB[cur][(wn * 64 + i * 16 + (lane & 15)) * 32 + (lane >> 4) * 8];
#pragma unroll
        for (int i = 0; i < 4; ++i)
            aF[i] = *(const bf16x8*)&sA[cur][(wm * 64 + i * 16 + (lane & 15)) * 32 + (lane >> 4) * 8];
#pragma unroll
        for (int mi = 0; mi < 4; ++mi)
#pragma unroll
            for (int ni = 0; ni < 4; ++ni)
                acc[mi][ni] = __builtin_amdgcn_mfma_f32_16x16x32_bf16(aF[mi], bF[ni], acc[mi][ni], 0, 0, 0);
        __syncthreads();
        cur ^= 1;
    }

    const int lrow = lane & 15;
    if (isK) {
        // fused RoPE epilogue: d = col&127, pair in lane^1, pos = row&2047
        float inv4[4];
#pragma unroll
        for (int ni = 0; ni < 4; ++ni) {
            int d = (wn * 64 + ni * 16 + lrow) & 127;
            inv4[ni] = exp2f(NL2T * (float)(d >> 1));
        }
        const bool ev = (lrow & 1) == 0;
#pragma unroll
        for (int mi = 0; mi < 4; ++mi)
#pragma unroll
            for (int ni = 0; ni < 4; ++ni)
#pragma unroll
                for (int r = 0; r < 4; ++r) {
                    int row = m0 + wm * 64 + mi * 16 + (lane >> 4) * 4 + r;
                    int col = n0 + wn * 64 + ni * 16 + lrow;
                    float v = acc[mi][ni][r];
                    float p = __shfl_xor(v, 1, 64);
                    float ang = (float)(row & (SEQ - 1)) * inv4[ni];
                    float sn = __sinf(ang), cs = __cosf(ang);
                    float o = v * cs + (ev ? -p * sn : p * sn);
                    out0[(size_t)row * N + col] = (bf16)o;
                }
    } else {
#pragma unroll
        for (int mi = 0; mi < 4; ++mi)
#pragma unroll
            for (int ni = 0; ni < 4; ++ni)
#pragma unroll
                for (int r = 0; r < 4; ++r) {
                    int row = m0 + wm * 64 + mi * 16 + (lane >> 4) * 4 + r;
                    int col = n0 + wn * 64 + ni * 16 + lrow;
                    out0[(size_t)row * N + col] = (bf16)acc[mi][ni][r];
                }
    }
}

// ---------------- 256x256 deep-pipelined GEMM (R7 schedule, best measured) --
// Phase p (one 32-wide K-half): [12 ds_read B-first][stage next region]
// [vmcnt(4)][s_barrier][lgkmcnt(0)+sched_barrier][setprio + 32 MFMA].
// MODE 0: bf16 out. MODE 1: bf16 out + fused RoPE (oscale folded). MODE 2: f32.
template <int MODE>
__global__ __launch_bounds__(512, 2) void gemm8(const bf16* __restrict__ A,
                                                const bf16* __restrict__ Bt,
                                                void* __restrict__ outp, int N,
                                                float oscale) {
    __shared__ alignas(16) char sA[2][2][16384];
    __shared__ alignas(16) char sB[2][2][16384];
    const int tid = threadIdx.x, lane = tid & 63;
    const int wid = tid >> 6;
    const int wm = wid >> 2, wn = wid & 3;
    const int m0 = blockIdx.y * 256, n0 = blockIdx.x * 256;
    const int lrow = lane & 15, hc = lane >> 4;
    const int rowbase = ((lrow >> 1) * 128) +
                        (((((lrow & 1) << 2) | hc) ^ (lrow >> 1)) << 4);
    const int NT = GK / 64;

    auto stageR = [&](int t, int kh) {
#pragma unroll
        for (int it = 0; it < 2; ++it) {
            int sl = it * 512 + tid;              // 16B chunk id 0..1023
            int PRr = sl >> 3, ps = sl & 7;       // pair-row, phys slot
            int lsl = ps ^ (PRr & 7);             // logical slot (involution)
            int r = PRr * 2 + (lsl >> 2);         // logical row 0..255
            int cc = lsl & 3;                     // 16B col-chunk 0..3
            size_t koff = (size_t)t * 64 + kh * 32 + cc * 8;
            gload_lds16(A + (size_t)(m0 + r) * GK + koff, &sA[t & 1][kh][sl * 16]);
            gload_lds16(Bt + (size_t)(n0 + r) * GK + koff, &sB[t & 1][kh][sl * 16]);
        }
    };

    f32x4 acc[8][4] = {};
    bf16x8 af[8], bfr[4];

    auto phread = [&](int t, int kh) {
        const char* Ab = &sA[t & 1][kh][0];
        const char* Bb = &sB[t & 1][kh][0];
#pragma unroll
        for (int ni = 0; ni < 4; ++ni)
            bfr[ni] = *(const bf16x8*)(Bb + wn * 4096 + ni * 1024 + rowbase);
#pragma unroll
        for (int mi = 0; mi < 8; ++mi)
            af[mi] = *(const bf16x8*)(Ab + wm * 8192 + mi * 1024 + rowbase);
    };
    auto phmfma = [&]() {
        __builtin_amdgcn_s_barrier();
        asm volatile("s_waitcnt lgkmcnt(0)" ::: "memory");
        __builtin_amdgcn_sched_barrier(0);
        __builtin_amdgcn_s_setprio(1);
#pragma unroll
        for (int mi = 0; mi < 8; ++mi)
#pragma unroll
            for (int ni = 0; ni < 4; ++ni)
                acc[mi][ni] = __builtin_amdgcn_mfma_f32_16x16x32_bf16(af[mi], bfr[ni], acc[mi][ni], 0, 0, 0);
        __builtin_amdgcn_s_setprio(0);
    };

    // prologue: stage both halves of tile 0 (8 VMEM/thread)
    stageR(0, 0); stageR(0, 1);
    asm volatile("s_waitcnt vmcnt(4)" ::: "memory");   // own (0,0) retired
    __builtin_amdgcn_s_barrier();                      // all waves' (0,0) landed

    for (int t = 0; t < NT; ++t) {
#pragma unroll
        for (int kh = 0; kh < 2; ++kh) {
            phread(t, kh);
            if (t + 1 < NT) {
                stageR(t + 1, kh);
                asm volatile("s_waitcnt vmcnt(4)" ::: "memory");
            } else {
                asm volatile("s_waitcnt vmcnt(0)" ::: "memory");
            }
            phmfma();
        }
    }

    // epilogue
    if constexpr (MODE == 1) {
        // fused RoPE: pair element (d^1) is in adjacent lane; fp32 pre-round
        float inv4[4];
#pragma unroll
        for (int ni = 0; ni < 4; ++ni) {
            int d = ((wn & 1) * 64 + ni * 16 + lrow) & 127;
            inv4[ni] = exp2f(NL2T * (float)(d >> 1));
        }
        const bool ev = (lrow & 1) == 0;
#pragma unroll
        for (int mi = 0; mi < 8; ++mi)
#pragma unroll
            for (int ni = 0; ni < 4; ++ni)
#pragma unroll
                for (int r = 0; r < 4; ++r) {
                    int row = m0 + wm * 128 + mi * 16 + hc * 4 + r;
                    int col = n0 + wn * 64 + ni * 16 + lrow;
                    float v = acc[mi][ni][r];
                    float p = __shfl_xor(v, 1, 64);
                    float ang = (float)(row & (SEQ - 1)) * inv4[ni];
                    float sn = __sinf(ang), cs = __cosf(ang);
                    float o = v * cs + (ev ? -p * sn : p * sn);
                    ((bf16*)outp)[(size_t)row * N + col] = (bf16)(o * oscale);
                }
    } else {
#pragma unroll
        for (int mi = 0; mi < 8; ++mi)
#pragma unroll
            for (int ni = 0; ni < 4; ++ni)
#pragma unroll
                for (int r = 0; r < 4; ++r) {
                    int row = m0 + wm * 128 + mi * 16 + hc * 4 + r;
                    int col = n0 + wn * 64 + ni * 16 + lrow;
                    if constexpr (MODE == 2)
                        ((float*)outp)[(size_t)row * N + col] = acc[mi][ni][r];
                    else
                        ((bf16*)outp)[(size_t)row * N + col] = (bf16)acc[mi][ni][r];
                }
    }
}

// ---------------- flash attention, GQA, causal ----------------
// grid: 512 = b(2) * h(32) * pair(8); 8 waves x 16 q-rows = 128 q-rows/pass;
// each block runs two passes (q-tile pr and 15-pr) -> exactly 34 KV rounds each.
// Swapped QK^T (S^T). Q pre-scaled by 1/sqrt(d)*log2(e) -> exp2-domain softmax.
// Wave-uniform diag split + defer-max (THR=8). l kept as per-lane PARTIAL sum
// (hi-quarter); cross-hi reduction deferred to the epilogue (al is hi-uniform,
// so partials stay consistently scaled) — saves 2 shuffles per tile.
__global__ __launch_bounds__(512, 4) void attn_fwd(const bf16* __restrict__ q,
                                                   const bf16* __restrict__ k,
                                                   const bf16* __restrict__ vt,
                                                   bf16* __restrict__ o) {
    __shared__ alignas(16) bf16 sK[2][64 * 128];   // [kv][d], XOR-swizzled source
    __shared__ alignas(16) bf16 sV[2][128 * 64];   // [d][kv], XOR-swizzled source
    __shared__ alignas(16) bf16 sP[8][16 * 64];    // per-wave P[q][kv], swizzled
    const int tid = threadIdx.x, lane = tid & 63, wid = tid >> 6;
    const int bi = blockIdx.x;
    const int pr = bi & 7;
    const int h = (bi >> 3) & 31;
    const int b = bi >> 8;
    const int kvh = h >> 2;

    const bf16* kb0 = k + (size_t)b * SEQ * (NKV * HD) + kvh * HD;
    const bf16* vb0 = vt + (size_t)(kvh * HD) * MTOT + (size_t)b * SEQ;

    auto stage = [&](int bf, int tt) {
#pragma unroll
        for (int it = 0; it < 2; ++it) {
            int slot = it * 512 + tid;
            int row = slot >> 4, s = slot & 15;
            gload_lds16(kb0 + (size_t)(tt * 64 + row) * (NKV * HD) + ((s ^ (row & 7)) * 8),
                        &sK[bf][slot * 8]);
        }
#pragma unroll
        for (int it = 0; it < 2; ++it) {
            int slot = it * 512 + tid;
            int row = slot >> 3, s = slot & 7;
            gload_lds16(vb0 + (size_t)row * MTOT + tt * 64 + ((s ^ (row & 7)) * 8),
                        &sV[bf][slot * 8]);
        }
    };

    auto pass = [&](int qt) {
        const int qb0 = qt * 128;
        const int nt = 2 * qt + 2;
        const int qw = qb0 + wid * 16;        // wave's first q row (16-aligned)
        const bf16* qp = q + ((size_t)(b * SEQ + qw + (lane & 15))) * DIM
                           + h * HD + (lane >> 4) * 8;
        bf16x8 aQ[4];
#pragma unroll
        for (int ks = 0; ks < 4; ++ks) aQ[ks] = *(const bf16x8*)(qp + ks * 32);

        f32x4 accO[8] = {};
        float m_r = -1e30f, l_r = 0.f;   // m: hi-uniform; l: per-lane PARTIAL
        const int qglob = qw + (lane & 15);
        char* pb = (char*)&sP[wid][0];
        const int q7s = (lane & 7) << 4;
        const int hi = lane >> 4;

        stage(0, 0);
        __syncthreads();
        int cur = 0;
        for (int tt = 0; tt < nt; ++tt) {
            if (tt + 1 < nt) stage(cur ^ 1, tt + 1);
            // skip tiles fully above this wave's rows (t0 and qw both 16-aligned)
            if (tt * 64 <= qw) {
                // S^T = mfma(K, Q): frag nt2 -> kv = tt*64+nt2*16+hi*4+r, col q = lane&15
                f32x4 accS[4] = {};
#pragma unroll
                for (int nt2 = 0; nt2 < 4; ++nt2) {
                    int kr = nt2 * 16 + (lane & 15);
#pragma unroll
                    for (int ks = 0; ks < 4; ++ks) {
                        int slog = ks * 4 + hi;
                        bf16x8 bK = *(const bf16x8*)&sK[cur][kr * 128 + ((slog ^ (kr & 7)) * 8)];
                        accS[nt2] = __builtin_amdgcn_mfma_f32_16x16x32_bf16(bK, aQ[ks], accS[nt2], 0, 0, 0);
                    }
                }

                // lane-local max over 16 kv values; mask only on diagonal tiles
                const bool diag = (tt * 64 + 63 > qw);
                float mx = -1e30f;
                if (diag) {
                    const int kvb = tt * 64 + hi * 4;
#pragma unroll
                    for (int nt2 = 0; nt2 < 4; ++nt2)
#pragma unroll
                        for (int r = 0; r < 4; ++r) {
                            float v = accS[nt2][r];
                            if (kvb + nt2 * 16 + r > qglob) v = -1e30f;
                            accS[nt2][r] = v;
                            mx = fmaxf(mx, v);
                        }
                } else {
#pragma unroll
                    for (int nt2 = 0; nt2 < 4; ++nt2)
#pragma unroll
                        for (int r = 0; r < 4; ++r) mx = fmaxf(mx, accS[nt2][r]);
                }
                mx = fmaxf(mx, __shfl_xor(mx, 16, 64));
                mx = fmaxf(mx, __shfl_xor(mx, 32, 64));

                // defer-max: only rescale when tile max advances past m_r + 8
                if (!__all(mx <= m_r + 8.f)) {
                    float mn = fmaxf(m_r, mx);
                    float al = __builtin_amdgcn_exp2f(m_r - mn);
                    m_r = mn;
                    l_r *= al;
                    float al4[4];
#pragma unroll
                    for (int r = 0; r < 4; ++r) al4[r] = __shfl(al, hi * 4 + r, 64);
#pragma unroll
                    for (int d2 = 0; d2 < 8; ++d2)
#pragma unroll
                        for (int r = 0; r < 4; ++r) accO[d2][r] *= al4[r];
                }

                float rs = 0.f;
#pragma unroll
                for (int nt2 = 0; nt2 < 4; ++nt2)
#pragma unroll
                    for (int r = 0; r < 4; ++r) {
                        float p = __builtin_amdgcn_exp2f(accS[nt2][r] - m_r);
                        accS[nt2][r] = p;
                        rs += p;
                    }
                l_r += rs;   // per-lane partial; cross-hi reduce in epilogue

                // P-write: lane holds 4 contiguous kv per frag -> b64 stores
#pragma unroll
                for (int nt2 = 0; nt2 < 4; ++nt2) {
                    bf16x4 pv;
                    pv[0] = (bf16)accS[nt2][0]; pv[1] = (bf16)accS[nt2][1];
                    pv[2] = (bf16)accS[nt2][2]; pv[3] = (bf16)accS[nt2][3];
                    *(bf16x4*)(pb + (lane & 15) * 128 + ((nt2 * 32 + hi * 8) ^ q7s)) = pv;
                }

                // PV: O[16 x 128] += P[16 x 64] * V[64 x 128]
                bf16x8 aP[2];
#pragma unroll
                for (int kk = 0; kk < 2; ++kk)
                    aP[kk] = *(const bf16x8*)(pb + (lane & 15) * 128 + ((kk * 64 + hi * 16) ^ q7s));
#pragma unroll
                for (int d2 = 0; d2 < 8; ++d2) {
#pragma unroll
                    for (int kk = 0; kk < 2; ++kk) {
                        int dv = d2 * 16 + (lane & 15);
                        int phys = (kk * 4 + hi) ^ (dv & 7);
                        bf16x8 bV = *(const bf16x8*)&sV[cur][dv * 64 + phys * 8];
                        accO[d2] = __builtin_amdgcn_mfma_f32_16x16x32_bf16(aP[kk], bV, accO[d2], 0, 0, 0);
                    }
                }
            }
            __syncthreads();
            cur ^= 1;
        }

        // epilogue: reduce l partials across hi, normalize + store bf16
        l_r += __shfl_xor(l_r, 16, 64);
        l_r += __shfl_xor(l_r, 32, 64);
        float linv[4];
#pragma unroll
        for (int r = 0; r < 4; ++r) linv[r] = 1.f / __shfl(l_r, hi * 4 + r, 64);
        size_t orow = (size_t)(b * SEQ + qb0 + wid * 16 + hi * 4) * DIM
                    + h * HD + (lane & 15);
#pragma unroll
        for (int d2 = 0; d2 < 8; ++d2)
#pragma unroll
            for (int r = 0; r < 4; ++r)
                o[orow + (size_t)r * DIM + d2 * 16] = (bf16)(accO[d2][r] * linv[r]);
    };

    pass(pr);
    pass(15 - pr);
}

// ---------------- launch ----------------
extern "C" void kernel_launch(void* const* d_in, const int* in_sizes, int n_in,
                              void* d_out, int out_size, void* d_ws, size_t ws_size,
                              hipStream_t stream) {
    const float* x  = (const float*)d_in[0];
    const float* wq = (const float*)d_in[1];
    const float* wk = (const float*)d_in[2];
    const float* wv = (const float*)d_in[3];
    const float* wo = (const float*)d_in[4];
    float* out = (float*)d_out;

    char* ws = (char*)d_ws;
    size_t off = 0;
    bf16* xb  = (bf16*)(ws + off); off += (size_t)MTOT * DIM * 2;   // 32 MiB (reused as attn_out)
    bf16* wqt = (bf16*)(ws + off); off += (size_t)DIM * DIM * 2;    // 32 MiB (reused as wo_t)
    bf16* wkt = (bf16*)(ws + off); off += (size_t)1024 * DIM * 2;   // 8 MiB
    bf16* wvt = (bf16*)(ws + off); off += (size_t)1024 * DIM * 2;   // 8 MiB
    bf16* qb  = (bf16*)(ws + off); off += (size_t)MTOT * DIM * 2;   // 32 MiB
    bf16* kb  = (bf16*)(ws + off); off += (size_t)MTOT * 1024 * 2;  // 8 MiB
    bf16* vtb = (bf16*)(ws + off); off += (size_t)MTOT * 1024 * 2;  // 8 MiB  V^T [1024][4096]
    bf16* ao = xb;  // attention output reuses x_bf16

    // 1/sqrt(HD) * log2(e): folds softmax scale + exp->exp2 conversion into Q
    const float SCALE2 = 0.08838834764831845f * 1.44269504088896340f;

    // fused prep: x convert (8192) + wq (4096) + wk (1024) + wv (1024)
    prep<<<8192 + 4096 + 1024 + 1024, 256, 0, stream>>>(x, wq, wk, wv, xb, wqt, wkt, wvt);

    // Q proj with fused RoPE+scale: 4096^3 on the 256^2 pipelined kernel
    gemm8<1><<<dim3(DIM / 256, MTOT / 256), 512, 0, stream>>>(xb, wqt, qb, DIM, SCALE2);

    // K proj (RoPE fused) + V^T proj merged: 512 blocks -> 2 blocks/CU
    gemm_kv<<<512, 256, 0, stream>>>(xb, wkt, wvt, kb, vtb);

    // wo transpose -> wqt space (free after Q proj); separate launch (R15 lesson)
    tconv64<<<dim3(DIM / 64, DIM / 64), 256, 0, stream>>>(wo, wqt, DIM, DIM);

    attn_fwd<<<BATCH * NH * 8, 512, 0, stream>>>(qb, kb, vtb, ao);

    // out proj: fp32 output on the 256^2 kernel (wqt now holds wo^T)
    gemm8<2><<<dim3(DIM / 256, MTOT / 256), 512, 0, stream>>>(ao, wqt, out, DIM, 1.0f);
}

// Round 17
// 502.675 us; speedup vs baseline: 1.0406x; 1.0107x over previous
//
#include <hip/hip_runtime.h>

#define DIM 4096
#define HD 128
#define NH 32
#define NKV 8
#define SEQ 2048
#define BATCH 2
#define MTOT (BATCH*SEQ)   // 4096 rows total
#define GK DIM             // K dim of every GEMM

typedef __bf16 bf16;
typedef __bf16 bf16x4 __attribute__((ext_vector_type(4)));
typedef __bf16 bf16x8 __attribute__((ext_vector_type(8)));
typedef float f32x4 __attribute__((ext_vector_type(4)));

#define NL2T (-13.287712379549449f / 64.f)   // -log2(10000)/(HD/2)

__device__ __forceinline__ void gload_lds16(const void* g, void* l) {
    __builtin_amdgcn_global_load_lds(
        (const __attribute__((address_space(1))) void*)g,
        (__attribute__((address_space(3))) void*)l, 16, 0, 0);
}

// ---------------- 64x64 transpose-convert tile: fp32 [K][N] -> bf16 [N][K] --
__device__ __forceinline__ void tconv64_tile(const float* __restrict__ in,
                                             bf16* __restrict__ out,
                                             int N, int K, int bx, int by,
                                             float t[64][65], int tid) {
    int rr = tid >> 4;              // 0..15
    int cc = (tid & 15) * 4;        // 0..60
    const float* ip = in + ((size_t)(by * 64 + rr)) * N + bx * 64 + cc;
#pragma unroll
    for (int p = 0; p < 4; ++p) {
        float4 v = *(const float4*)(ip + (size_t)p * 16 * N);
        t[rr + p * 16][cc + 0] = v.x;
        t[rr + p * 16][cc + 1] = v.y;
        t[rr + p * 16][cc + 2] = v.z;
        t[rr + p * 16][cc + 3] = v.w;
    }
    __syncthreads();
#pragma unroll
    for (int p = 0; p < 4; ++p) {
        int n = rr + p * 16;
        bf16x4 o;
#pragma unroll
        for (int j = 0; j < 4; ++j) o[j] = (bf16)t[cc + j][n];
        *(bf16x4*)(out + (size_t)(bx * 64 + n) * K + by * 64 + cc) = o;
    }
}

// ---------------- fused prep: x->bf16 convert + wq/wk/wv transpose-convert --
__global__ __launch_bounds__(256) void prep(const float* __restrict__ x,
                                            const float* __restrict__ wq,
                                            const float* __restrict__ wk,
                                            const float* __restrict__ wv,
                                            bf16* __restrict__ xb,
                                            bf16* __restrict__ wqt,
                                            bf16* __restrict__ wkt,
                                            bf16* __restrict__ wvt) {
    __shared__ float t[64][65];
    const int bid = blockIdx.x, tid = threadIdx.x;
    if (bid < 8192) {                       // x convert: 8192*256*8 = MTOT*DIM
        int i = bid * 256 + tid;
        const float4* p = (const float4*)(x + (size_t)i * 8);
        float4 a = p[0], b = p[1];
        bf16x8 v;
        v[0]=(bf16)a.x; v[1]=(bf16)a.y; v[2]=(bf16)a.z; v[3]=(bf16)a.w;
        v[4]=(bf16)b.x; v[5]=(bf16)b.y; v[6]=(bf16)b.z; v[7]=(bf16)b.w;
        *(bf16x8*)(xb + (size_t)i * 8) = v;
    } else if (bid < 8192 + 4096) {         // wq: 64x64 tiles
        int b2 = bid - 8192;
        tconv64_tile(wq, wqt, DIM, DIM, b2 & 63, b2 >> 6, t, tid);
    } else if (bid < 8192 + 4096 + 1024) {  // wk
        int b2 = bid - (8192 + 4096);
        tconv64_tile(wk, wkt, 1024, DIM, b2 & 15, b2 >> 4, t, tid);
    } else {                                // wv
        int b2 = bid - (8192 + 4096 + 1024);
        tconv64_tile(wv, wvt, 1024, DIM, b2 & 15, b2 >> 4, t, tid);
    }
}

// ---------------- standalone transpose-convert (wo, after Q-proj) ----------
__global__ __launch_bounds__(256) void tconv64(const float* __restrict__ in,
                                               bf16* __restrict__ out, int N, int K) {
    __shared__ float t[64][65];
    tconv64_tile(in, out, N, K, blockIdx.x, blockIdx.y, t, threadIdx.x);
}

// ---------------- merged K-proj + V^T-proj (one 512-block launch) ----------
__global__ __launch_bounds__(256, 2) void gemm_kv(const bf16* __restrict__ xb,
                                                  const bf16* __restrict__ wkt,
                                                  const bf16* __restrict__ wvt,
                                                  bf16* __restrict__ kb,
                                                  bf16* __restrict__ vtb) {
    __shared__ alignas(16) bf16 sA[2][128 * 32];
    __shared__ alignas(16) bf16 sB[2][128 * 32];
    const int tid = threadIdx.x;
    const int lane = tid & 63, wid = tid >> 6;
    const int wm = wid >> 1, wn = wid & 1;

    const bf16 *A, *Bt;
    bf16* out0;
    int N, m0, n0;
    const int bid = blockIdx.x;
    const bool isK = (bid < 256);
    if (isK) {
        A = xb; Bt = wkt; out0 = kb; N = 1024;
        m0 = (bid >> 3) * 128; n0 = (bid & 7) * 128;
    } else {
        int b2 = bid - 256;
        A = wvt; Bt = xb; out0 = vtb; N = MTOT;
        m0 = (b2 >> 5) * 128; n0 = (b2 & 31) * 128;
    }

    auto stage = [&](int buf, int kt) {
#pragma unroll
        for (int it = 0; it < 2; ++it) {
            int slot = it * 256 + tid;
            int row = slot >> 2, s = slot & 3;
            gload_lds16(A + (size_t)(m0 + row) * GK + kt * 32 + s * 8, &sA[buf][slot * 8]);
            gload_lds16(Bt + (size_t)(n0 + row) * GK + kt * 32 + s * 8, &sB[buf][slot * 8]);
        }
    };

    f32x4 acc[4][4] = {};
    stage(0, 0);
    __syncthreads();
    int cur = 0;
    for (int kt = 0; kt < GK / 32; ++kt) {
        if (kt + 1 < GK / 32) stage(cur ^ 1, kt + 1);
        bf16x8 bF[4], aF[4];
#pragma unroll
        for (int i = 0; i < 4; ++i)
            bF[i] = *(const bf16x8*)&sB[cur][(wn * 64 + i * 16 + (lane & 15)) * 32 + (lane >> 4) * 8];
#pragma unroll
        for (int i = 0; i < 4; ++i)
            aF[i] = *(const bf16x8*)&sA[cur][(wm * 64 + i * 16 + (lane & 15)) * 32 + (lane >> 4) * 8];
#pragma unroll
        for (int mi = 0; mi < 4; ++mi)
#pragma unroll
            for (int ni = 0; ni < 4; ++ni)
                acc[mi][ni] = __builtin_amdgcn_mfma_f32_16x16x32_bf16(aF[mi], bF[ni], acc[mi][ni], 0, 0, 0);
        __syncthreads();
        cur ^= 1;
    }

    const int lrow = lane & 15;
    if (isK) {
        float inv4[4];
#pragma unroll
        for (int ni = 0; ni < 4; ++ni) {
            int d = (wn * 64 + ni * 16 + lrow) & 127;
            inv4[ni] = exp2f(NL2T * (float)(d >> 1));
        }
        const bool ev = (lrow & 1) == 0;
#pragma unroll
        for (int mi = 0; mi < 4; ++mi)
#pragma unroll
            for (int ni = 0; ni < 4; ++ni)
#pragma unroll
                for (int r = 0; r < 4; ++r) {
                    int row = m0 + wm * 64 + mi * 16 + (lane >> 4) * 4 + r;
                    int col = n0 + wn * 64 + ni * 16 + lrow;
                    float v = acc[mi][ni][r];
                    float p = __shfl_xor(v, 1, 64);
                    float ang = (float)(row & (SEQ - 1)) * inv4[ni];
                    float sn = __sinf(ang), cs = __cosf(ang);
                    float o = v * cs + (ev ? -p * sn : p * sn);
                    out0[(size_t)row * N + col] = (bf16)o;
                }
    } else {
#pragma unroll
        for (int mi = 0; mi < 4; ++mi)
#pragma unroll
            for (int ni = 0; ni < 4; ++ni)
#pragma unroll
                for (int r = 0; r < 4; ++r) {
                    int row = m0 + wm * 64 + mi * 16 + (lane >> 4) * 4 + r;
                    int col = n0 + wn * 64 + ni * 16 + lrow;
                    out0[(size_t)row * N + col] = (bf16)acc[mi][ni][r];
                }
    }
}

// ---------------- 256x256 deep-pipelined GEMM (R7 schedule, best measured) --
template <int MODE>
__global__ __launch_bounds__(512, 2) void gemm8(const bf16* __restrict__ A,
                                                const bf16* __restrict__ Bt,
                                                void* __restrict__ outp, int N,
                                                float oscale) {
    __shared__ alignas(16) char sA[2][2][16384];
    __shared__ alignas(16) char sB[2][2][16384];
    const int tid = threadIdx.x, lane = tid & 63;
    const int wid = tid >> 6;
    const int wm = wid >> 2, wn = wid & 3;
    const int m0 = blockIdx.y * 256, n0 = blockIdx.x * 256;
    const int lrow = lane & 15, hc = lane >> 4;
    const int rowbase = ((lrow >> 1) * 128) +
                        (((((lrow & 1) << 2) | hc) ^ (lrow >> 1)) << 4);
    const int NT = GK / 64;

    auto stageR = [&](int t, int kh) {
#pragma unroll
        for (int it = 0; it < 2; ++it) {
            int sl = it * 512 + tid;              // 16B chunk id 0..1023
            int PRr = sl >> 3, ps = sl & 7;       // pair-row, phys slot
            int lsl = ps ^ (PRr & 7);             // logical slot (involution)
            int r = PRr * 2 + (lsl >> 2);         // logical row 0..255
            int cc = lsl & 3;                     // 16B col-chunk 0..3
            size_t koff = (size_t)t * 64 + kh * 32 + cc * 8;
            gload_lds16(A + (size_t)(m0 + r) * GK + koff, &sA[t & 1][kh][sl * 16]);
            gload_lds16(Bt + (size_t)(n0 + r) * GK + koff, &sB[t & 1][kh][sl * 16]);
        }
    };

    f32x4 acc[8][4] = {};
    bf16x8 af[8], bfr[4];

    auto phread = [&](int t, int kh) {
        const char* Ab = &sA[t & 1][kh][0];
        const char* Bb = &sB[t & 1][kh][0];
#pragma unroll
        for (int ni = 0; ni < 4; ++ni)
            bfr[ni] = *(const bf16x8*)(Bb + wn * 4096 + ni * 1024 + rowbase);
#pragma unroll
        for (int mi = 0; mi < 8; ++mi)
            af[mi] = *(const bf16x8*)(Ab + wm * 8192 + mi * 1024 + rowbase);
    };
    auto phmfma = [&]() {
        __builtin_amdgcn_s_barrier();
        asm volatile("s_waitcnt lgkmcnt(0)" ::: "memory");
        __builtin_amdgcn_sched_barrier(0);
        __builtin_amdgcn_s_setprio(1);
#pragma unroll
        for (int mi = 0; mi < 8; ++mi)
#pragma unroll
            for (int ni = 0; ni < 4; ++ni)
                acc[mi][ni] = __builtin_amdgcn_mfma_f32_16x16x32_bf16(af[mi], bfr[ni], acc[mi][ni], 0, 0, 0);
        __builtin_amdgcn_s_setprio(0);
    };

    stageR(0, 0); stageR(0, 1);
    asm volatile("s_waitcnt vmcnt(4)" ::: "memory");
    __builtin_amdgcn_s_barrier();

    for (int t = 0; t < NT; ++t) {
#pragma unroll
        for (int kh = 0; kh < 2; ++kh) {
            phread(t, kh);
            if (t + 1 < NT) {
                stageR(t + 1, kh);
                asm volatile("s_waitcnt vmcnt(4)" ::: "memory");
            } else {
                asm volatile("s_waitcnt vmcnt(0)" ::: "memory");
            }
            phmfma();
        }
    }

    if constexpr (MODE == 1) {
        float inv4[4];
#pragma unroll
        for (int ni = 0; ni < 4; ++ni) {
            int d = ((wn & 1) * 64 + ni * 16 + lrow) & 127;
            inv4[ni] = exp2f(NL2T * (float)(d >> 1));
        }
        const bool ev = (lrow & 1) == 0;
#pragma unroll
        for (int mi = 0; mi < 8; ++mi)
#pragma unroll
            for (int ni = 0; ni < 4; ++ni)
#pragma unroll
                for (int r = 0; r < 4; ++r) {
                    int row = m0 + wm * 128 + mi * 16 + hc * 4 + r;
                    int col = n0 + wn * 64 + ni * 16 + lrow;
                    float v = acc[mi][ni][r];
                    float p = __shfl_xor(v, 1, 64);
                    float ang = (float)(row & (SEQ - 1)) * inv4[ni];
                    float sn = __sinf(ang), cs = __cosf(ang);
                    float o = v * cs + (ev ? -p * sn : p * sn);
                    ((bf16*)outp)[(size_t)row * N + col] = (bf16)(o * oscale);
                }
    } else {
#pragma unroll
        for (int mi = 0; mi < 8; ++mi)
#pragma unroll
            for (int ni = 0; ni < 4; ++ni)
#pragma unroll
                for (int r = 0; r < 4; ++r) {
                    int row = m0 + wm * 128 + mi * 16 + hc * 4 + r;
                    int col = n0 + wn * 64 + ni * 16 + lrow;
                    if constexpr (MODE == 2)
                        ((float*)outp)[(size_t)row * N + col] = acc[mi][ni][r];
                    else
                        ((bf16*)outp)[(size_t)row * N + col] = (bf16)acc[mi][ni][r];
                }
    }
}

// ---------------- flash attention, GQA, causal ----------------
// grid: 512 = b(2) * h(32) * pair(8); 4 waves x 32 q-rows = 128 q-rows/pass;
// passes (pr, 15-pr) -> 34 KV rounds/block. 32 q/wave doubles bK/bV frag
// reuse: 44 LDS ops per 64 MFMA (was 38 per 32). qh in {0,1} indexes the two
// 16-row q-halves; all arrays statically unrolled. Swizzle keys use
// (lane&15)&7 = row&7 for both halves (write/read consistent).
__global__ __launch_bounds__(256, 2) void attn_fwd(const bf16* __restrict__ q,
                                                   const bf16* __restrict__ k,
                                                   const bf16* __restrict__ vt,
                                                   bf16* __restrict__ o) {
    __shared__ alignas(16) bf16 sK[2][64 * 128];   // [kv][d], XOR-swizzled source
    __shared__ alignas(16) bf16 sV[2][128 * 64];   // [d][kv], XOR-swizzled source
    __shared__ alignas(16) bf16 sP[4][32 * 64];    // per-wave P[q][kv], swizzled
    const int tid = threadIdx.x, lane = tid & 63, wid = tid >> 6;  // wid 0..3
    const int bi = blockIdx.x;
    const int pr = bi & 7;
    const int h = (bi >> 3) & 31;
    const int b = bi >> 8;
    const int kvh = h >> 2;

    const bf16* kb0 = k + (size_t)b * SEQ * (NKV * HD) + kvh * HD;
    const bf16* vb0 = vt + (size_t)(kvh * HD) * MTOT + (size_t)b * SEQ;

    auto stage = [&](int bf, int tt) {
#pragma unroll
        for (int it = 0; it < 4; ++it) {
            int slot = it * 256 + tid;
            int row = slot >> 4, s = slot & 15;
            gload_lds16(kb0 + (size_t)(tt * 64 + row) * (NKV * HD) + ((s ^ (row & 7)) * 8),
                        &sK[bf][slot * 8]);
        }
#pragma unroll
        for (int it = 0; it < 4; ++it) {
            int slot = it * 256 + tid;
            int row = slot >> 3, s = slot & 7;
            gload_lds16(vb0 + (size_t)row * MTOT + tt * 64 + ((s ^ (row & 7)) * 8),
                        &sV[bf][slot * 8]);
        }
    };

    auto pass = [&](int qt) {
        const int qb0 = qt * 128;
        const int nt = 2 * qt + 2;
        const int qw = qb0 + wid * 32;        // wave's first q row (32-aligned)
        const int qg = lane & 15, hi = lane >> 4;
        const bf16* qp = q + ((size_t)(b * SEQ + qw + qg)) * DIM + h * HD + hi * 8;
        bf16x8 aQ[2][4];
#pragma unroll
        for (int qh = 0; qh < 2; ++qh)
#pragma unroll
            for (int ks = 0; ks < 4; ++ks)
                aQ[qh][ks] = *(const bf16x8*)(qp + (size_t)qh * 16 * DIM + ks * 32);

        f32x4 accO[8][2] = {};
        float m_r[2] = {-1e30f, -1e30f};
        float l_r[2] = {0.f, 0.f};          // per-lane PARTIAL (hi-quarter)
        char* pb = (char*)&sP[wid][0];
        const int q7s = (qg & 7) << 4;

        stage(0, 0);
        __syncthreads();
        int cur = 0;
        for (int tt = 0; tt < nt; ++tt) {
            if (tt + 1 < nt) stage(cur ^ 1, tt + 1);
            if (tt * 64 <= qw) {
                // S^T = mfma(K, Q): accS[nt2][qh] -> kv = tt*64+nt2*16+hi*4+r,
                // q col = qh*16 + qg. bK read once, used for both qh.
                f32x4 accS[4][2] = {};
#pragma unroll
                for (int nt2 = 0; nt2 < 4; ++nt2) {
                    int kr = nt2 * 16 + qg;
#pragma unroll
                    for (int ks = 0; ks < 4; ++ks) {
                        int slog = ks * 4 + hi;
                        bf16x8 bK = *(const bf16x8*)&sK[cur][kr * 128 + ((slog ^ (kr & 7)) * 8)];
                        accS[nt2][0] = __builtin_amdgcn_mfma_f32_16x16x32_bf16(bK, aQ[0][ks], accS[nt2][0], 0, 0, 0);
                        accS[nt2][1] = __builtin_amdgcn_mfma_f32_16x16x32_bf16(bK, aQ[1][ks], accS[nt2][1], 0, 0, 0);
                    }
                }

                const bool diag = (tt * 64 + 63 > qw);
                float mx[2] = {-1e30f, -1e30f};
                if (diag) {
                    const int kvb = tt * 64 + hi * 4;
#pragma unroll
                    for (int nt2 = 0; nt2 < 4; ++nt2)
#pragma unroll
                        for (int r = 0; r < 4; ++r) {
                            int kvv = kvb + nt2 * 16 + r;
#pragma unroll
                            for (int qh = 0; qh < 2; ++qh) {
                                float v = accS[nt2][qh][r];
                                if (kvv > qw + qh * 16 + qg) v = -1e30f;
                                accS[nt2][qh][r] = v;
                                mx[qh] = fmaxf(mx[qh], v);
                            }
                        }
                } else {
#pragma unroll
                    for (int nt2 = 0; nt2 < 4; ++nt2)
#pragma unroll
                        for (int r = 0; r < 4; ++r)
#pragma unroll
                            for (int qh = 0; qh < 2; ++qh)
                                mx[qh] = fmaxf(mx[qh], accS[nt2][qh][r]);
                }
#pragma unroll
                for (int qh = 0; qh < 2; ++qh) {
                    mx[qh] = fmaxf(mx[qh], __shfl_xor(mx[qh], 16, 64));
                    mx[qh] = fmaxf(mx[qh], __shfl_xor(mx[qh], 32, 64));
                }

                // defer-max (THR=8) over both halves
                if (!__all(mx[0] <= m_r[0] + 8.f && mx[1] <= m_r[1] + 8.f)) {
                    float al[2], al4[2][4];
#pragma unroll
                    for (int qh = 0; qh < 2; ++qh) {
                        float mn = fmaxf(m_r[qh], mx[qh]);
                        al[qh] = __builtin_amdgcn_exp2f(m_r[qh] - mn);
                        m_r[qh] = mn;
                        l_r[qh] *= al[qh];
                    }
#pragma unroll
                    for (int qh = 0; qh < 2; ++qh)
#pragma unroll
                        for (int r = 0; r < 4; ++r)
                            al4[qh][r] = __shfl(al[qh], hi * 4 + r, 64);
#pragma unroll
                    for (int d2 = 0; d2 < 8; ++d2)
#pragma unroll
                        for (int qh = 0; qh < 2; ++qh)
#pragma unroll
                            for (int r = 0; r < 4; ++r)
                                accO[d2][qh][r] *= al4[qh][r];
                }

#pragma unroll
                for (int qh = 0; qh < 2; ++qh) {
                    float rs = 0.f;
#pragma unroll
                    for (int nt2 = 0; nt2 < 4; ++nt2)
#pragma unroll
                        for (int r = 0; r < 4; ++r) {
                            float p = __builtin_amdgcn_exp2f(accS[nt2][qh][r] - m_r[qh]);
                            accS[nt2][qh][r] = p;
                            rs += p;
                        }
                    l_r[qh] += rs;
                }

                // P-write: row = qh*16+qg; row&7 == qg&7 -> same swizzle key
#pragma unroll
                for (int nt2 = 0; nt2 < 4; ++nt2)
#pragma unroll
                    for (int qh = 0; qh < 2; ++qh) {
                        bf16x4 pv;
                        pv[0] = (bf16)accS[nt2][qh][0]; pv[1] = (bf16)accS[nt2][qh][1];
                        pv[2] = (bf16)accS[nt2][qh][2]; pv[3] = (bf16)accS[nt2][qh][3];
                        *(bf16x4*)(pb + (qh * 16 + qg) * 128 + ((nt2 * 32 + hi * 8) ^ q7s)) = pv;
                    }

                // PV: O[32 x 128] += P[32 x 64] * V[64 x 128]; bV reused 2x
                bf16x8 aP[2][2];
#pragma unroll
                for (int kk = 0; kk < 2; ++kk)
#pragma unroll
                    for (int qh = 0; qh < 2; ++qh)
                        aP[kk][qh] = *(const bf16x8*)(pb + (qh * 16 + qg) * 128 + ((kk * 64 + hi * 16) ^ q7s));
#pragma unroll
                for (int d2 = 0; d2 < 8; ++d2) {
#pragma unroll
                    for (int kk = 0; kk < 2; ++kk) {
                        int dv = d2 * 16 + qg;
                        int phys = (kk * 4 + hi) ^ (dv & 7);
                        bf16x8 bV = *(const bf16x8*)&sV[cur][dv * 64 + phys * 8];
                        accO[d2][0] = __builtin_amdgcn_mfma_f32_16x16x32_bf16(aP[kk][0], bV, accO[d2][0], 0, 0, 0);
                        accO[d2][1] = __builtin_amdgcn_mfma_f32_16x16x32_bf16(aP[kk][1], bV, accO[d2][1], 0, 0, 0);
                    }
                }
            }
            __syncthreads();
            cur ^= 1;
        }

        // epilogue: reduce l partials across hi, normalize + store bf16
        float linv[2][4];
#pragma unroll
        for (int qh = 0; qh < 2; ++qh) {
            l_r[qh] += __shfl_xor(l_r[qh], 16, 64);
            l_r[qh] += __shfl_xor(l_r[qh], 32, 64);
#pragma unroll
            for (int r = 0; r < 4; ++r)
                linv[qh][r] = 1.f / __shfl(l_r[qh], hi * 4 + r, 64);
        }
#pragma unroll
        for (int qh = 0; qh < 2; ++qh) {
            size_t orow = (size_t)(b * SEQ + qw + qh * 16 + hi * 4) * DIM
                        + h * HD + qg;
#pragma unroll
            for (int d2 = 0; d2 < 8; ++d2)
#pragma unroll
                for (int r = 0; r < 4; ++r)
                    o[orow + (size_t)r * DIM + d2 * 16] = (bf16)(accO[d2][qh][r] * linv[qh][r]);
        }
    };

    pass(pr);
    pass(15 - pr);
}

// ---------------- launch ----------------
extern "C" void kernel_launch(void* const* d_in, const int* in_sizes, int n_in,
                              void* d_out, int out_size, void* d_ws, size_t ws_size,
                              hipStream_t stream) {
    const float* x  = (const float*)d_in[0];
    const float* wq = (const float*)d_in[1];
    const float* wk = (const float*)d_in[2];
    const float* wv = (const float*)d_in[3];
    const float* wo = (const float*)d_in[4];
    float* out = (float*)d_out;

    char* ws = (char*)d_ws;
    size_t off = 0;
    bf16* xb  = (bf16*)(ws + off); off += (size_t)MTOT * DIM * 2;   // 32 MiB (reused as attn_out)
    bf16* wqt = (bf16*)(ws + off); off += (size_t)DIM * DIM * 2;    // 32 MiB (reused as wo_t)
    bf16* wkt = (bf16*)(ws + off); off += (size_t)1024 * DIM * 2;   // 8 MiB
    bf16* wvt = (bf16*)(ws + off); off += (size_t)1024 * DIM * 2;   // 8 MiB
    bf16* qb  = (bf16*)(ws + off); off += (size_t)MTOT * DIM * 2;   // 32 MiB
    bf16* kb  = (bf16*)(ws + off); off += (size_t)MTOT * 1024 * 2;  // 8 MiB
    bf16* vtb = (bf16*)(ws + off); off += (size_t)MTOT * 1024 * 2;  // 8 MiB  V^T [1024][4096]
    bf16* ao = xb;  // attention output reuses x_bf16

    const float SCALE2 = 0.08838834764831845f * 1.44269504088896340f;

    prep<<<8192 + 4096 + 1024 + 1024, 256, 0, stream>>>(x, wq, wk, wv, xb, wqt, wkt, wvt);

    gemm8<1><<<dim3(DIM / 256, MTOT / 256), 512, 0, stream>>>(xb, wqt, qb, DIM, SCALE2);

    gemm_kv<<<512, 256, 0, stream>>>(xb, wkt, wvt, kb, vtb);

    tconv64<<<dim3(DIM / 64, DIM / 64), 256, 0, stream>>>(wo, wqt, DIM, DIM);

    attn_fwd<<<BATCH * NH * 8, 256, 0, stream>>>(qb, kb, vtb, ao);

    gemm8<2><<<dim3(DIM / 256, MTOT / 256), 512, 0, stream>>>(ao, wqt, out, DIM, 1.0f);
}